// Round 5
// baseline (1806.103 us; speedup 1.0000x reference)
//
#include <hip/hip_runtime.h>
#include <hip/hip_bf16.h>

#define NEG_SLOPE 0.2f

__device__ __forceinline__ void atomAddF(float* p, float v) {
    unsafeAtomicAdd(p, v);   // hardware global_atomic_add_f32 on gfx950
}

// ---------- CSR build ----------
__global__ void k_hist(const int* __restrict__ dst, int E, int* __restrict__ deg) {
    int e = blockIdx.x * 256 + threadIdx.x;
    if (e < E) atomicAdd(&deg[dst[e]], 1);
}

// exclusive scan of deg[0..n) -> start[0..n], start[n] = total. single block.
__global__ __launch_bounds__(1024) void k_scan(const int* __restrict__ deg,
                                               int* __restrict__ start, int n) {
    __shared__ int wsum[16];
    __shared__ int carry_s;
    if (threadIdx.x == 0) carry_s = 0;
    __syncthreads();
    const int lane = threadIdx.x & 63;
    const int w = threadIdx.x >> 6;
    for (int base = 0; base < n; base += 1024) {
        int i = base + (int)threadIdx.x;
        int v = (i < n) ? deg[i] : 0;
        int s = v;
#pragma unroll
        for (int o = 1; o < 64; o <<= 1) {
            int u = __shfl_up(s, o);
            if (lane >= o) s += u;
        }
        if (lane == 63) wsum[w] = s;
        __syncthreads();
        if (w == 0) {
            int ws = (lane < 16) ? wsum[lane] : 0;
#pragma unroll
            for (int o = 1; o < 16; o <<= 1) {
                int u = __shfl_up(ws, o);
                if (lane >= o) ws += u;
            }
            if (lane < 16) wsum[lane] = ws;
        }
        __syncthreads();
        int carry = carry_s;
        int woff = (w == 0) ? 0 : wsum[w - 1];
        int incl = s + woff + carry;
        if (i < n) start[i] = incl - v;
        __syncthreads();
        if (threadIdx.x == 1023) carry_s = incl;
        __syncthreads();
    }
    if (threadIdx.x == 0) start[n] = carry_s;
}

__global__ void k_fill(const int* __restrict__ src, const int* __restrict__ dst, int E,
                       const int* __restrict__ start, int* __restrict__ cursor,
                       int* __restrict__ perm, int* __restrict__ src_sorted,
                       int* __restrict__ dst_sorted) {
    int e = blockIdx.x * 256 + threadIdx.x;
    if (e >= E) return;
    int d = dst[e];
    int idx = start[d] + atomicAdd(&cursor[d], 1);
    perm[idx] = e;
    src_sorted[idx] = src[e];
    dst_sorted[idx] = d;
}

// ---------- node transform: xl = h@Wl+bl, xr = h@Wr+br ----------
template <int DIN>
__global__ void k_node_transform(const float* __restrict__ h,
                                 const float* __restrict__ Wl, const float* __restrict__ bl,
                                 const float* __restrict__ Wr, const float* __restrict__ br,
                                 float* __restrict__ xl, float* __restrict__ xr, int n) {
    __shared__ float hs[4][DIN];
    int node0 = blockIdx.x * 4;
    int tid = threadIdx.x;
    for (int idx = tid; idx < 4 * DIN; idx += 256) {
        int ln = idx / DIN, k = idx % DIN;
        int node = node0 + ln;
        hs[ln][k] = (node < n) ? h[(long long)node * DIN + k] : 0.f;
    }
    __syncthreads();
    int ln = tid >> 6;
    int j = tid & 63;
    int node = node0 + ln;
    if (node >= n) return;
    float al = bl[j], ar = br[j];
#pragma unroll 8
    for (int k = 0; k < DIN; ++k) {
        float hv = hs[ln][k];
        al += hv * Wl[k * 64 + j];
        ar += hv * Wr[k * 64 + j];
    }
    xl[(long long)node * 64 + j] = al;
    xr[(long long)node * 64 + j] = ar;
}

// ---------- fused edge pass over dst-SORTED edges ----------
// 64 sorted edges/block. GEMM tile (as R4) -> score -> exp -> run-combined
// atomic accumulate into out_acc/denom. ACC_LOOP additionally accumulates
// the staged ea tile into loop_sum (self-loop mean numerator).
template <bool ACC_LOOP>
__global__ __launch_bounds__(256) void k_edge_fused(
    const float* __restrict__ xl, const float* __restrict__ xr,
    const float* __restrict__ eattr,
    const float* __restrict__ We, const float* __restrict__ att,
    const int* __restrict__ perm, const int* __restrict__ src_sorted,
    const int* __restrict__ dst_sorted, int E,
    float* __restrict__ denom, float* __restrict__ out_acc,
    float* __restrict__ loop_sum) {
    __shared__ float We_s[32 * 64];
    __shared__ float ea_T[32][68];
    __shared__ float att_s[64];
    __shared__ int s_s[64], d_s[64];

    const int tid = threadIdx.x;
    const int ge0 = blockIdx.x * 64;

    for (int i = tid; i < 2048; i += 256) We_s[i] = We[i];
    if (tid < 64) att_s[tid] = att[tid];
    if (tid >= 64 && tid < 128) {
        int eb = tid - 64, ge = ge0 + eb;
        s_s[eb] = (ge < E) ? src_sorted[ge] : 0;
    }
    if (tid >= 128 && tid < 192) {
        int eb = tid - 128, ge = ge0 + eb;
        d_s[eb] = (ge < E) ? dst_sorted[ge] : -1;
    }
    {
        int e = tid & 63;          // lane varies along e -> conflict-free banks
        int k0 = (tid >> 6) * 8;   // wave-uniform k chunk
        int ge = ge0 + e;
        float4 a = make_float4(0.f, 0.f, 0.f, 0.f), b = a;
        if (ge < E) {
            int pe = perm[ge];
            const float4* p = (const float4*)(eattr + (size_t)pe * 32 + k0);
            a = p[0]; b = p[1];
        }
        ea_T[k0 + 0][e] = a.x; ea_T[k0 + 1][e] = a.y; ea_T[k0 + 2][e] = a.z; ea_T[k0 + 3][e] = a.w;
        ea_T[k0 + 4][e] = b.x; ea_T[k0 + 5][e] = b.y; ea_T[k0 + 6][e] = b.z; ea_T[k0 + 7][e] = b.w;
    }
    __syncthreads();

    const int w = tid >> 6, l = tid & 63;
    const int t0 = (l & 15) * 4;            // channel group
    const int e0 = w * 16 + (l >> 4) * 4;   // edge group (4 sorted edges)

    float z[4][4];
#pragma unroll
    for (int j = 0; j < 4; ++j)
#pragma unroll
        for (int i = 0; i < 4; ++i) z[j][i] = 0.f;

#pragma unroll 8
    for (int k = 0; k < 32; ++k) {
        const float4 ev = *(const float4*)&ea_T[k][e0];
        const float4 wv = *(const float4*)&We_s[k * 64 + t0];
        const float ee[4] = {ev.x, ev.y, ev.z, ev.w};
        const float ww[4] = {wv.x, wv.y, wv.z, wv.w};
#pragma unroll
        for (int j = 0; j < 4; ++j)
#pragma unroll
            for (int i = 0; i < 4; ++i) z[j][i] += ee[j] * ww[i];
    }

    const float4 av = *(const float4*)&att_s[t0];
    const float aa[4] = {av.x, av.y, av.z, av.w};
    float v[4];
    float4 xls[4];
    int dd[4];
#pragma unroll
    for (int j = 0; j < 4; ++j) {
        const int eb = e0 + j;
        const int s = s_s[eb];
        dd[j] = d_s[eb];
        const int dsafe = (dd[j] >= 0) ? dd[j] : 0;
        const float4 xlv = *(const float4*)&xl[(size_t)s * 64 + t0];
        const float4 xrv = *(const float4*)&xr[(size_t)dsafe * 64 + t0];
        xls[j] = xlv;
        const float xll[4] = {xlv.x, xlv.y, xlv.z, xlv.w};
        const float xrr[4] = {xrv.x, xrv.y, xrv.z, xrv.w};
        float acc = 0.f;
#pragma unroll
        for (int i = 0; i < 4; ++i) {
            float zz = z[j][i] + xll[i] + xrr[i];
            zz = (zz > 0.f) ? zz : NEG_SLOPE * zz;
            acc += aa[i] * zz;
        }
        v[j] = acc;
    }
#pragma unroll
    for (int m = 1; m < 16; m <<= 1) {
#pragma unroll
        for (int j = 0; j < 4; ++j) v[j] += __shfl_xor(v[j], m);
    }

    // run-combined flush: edges within a slot are dst-sorted.
    {
        float4 racc = make_float4(0.f, 0.f, 0.f, 0.f);
        float rden = 0.f;
        int rkey = -1;
#pragma unroll
        for (int j = 0; j < 4; ++j) {
            const int d = dd[j];
            if (d != rkey) {
                if (rkey >= 0) {
                    float* p = out_acc + (size_t)rkey * 64 + t0;
                    atomAddF(p + 0, racc.x); atomAddF(p + 1, racc.y);
                    atomAddF(p + 2, racc.z); atomAddF(p + 3, racc.w);
                    if ((l & 15) == 0) atomAddF(&denom[rkey], rden);
                }
                rkey = d;
                racc = make_float4(0.f, 0.f, 0.f, 0.f);
                rden = 0.f;
            }
            if (rkey >= 0) {
                const float ex = __expf(v[j]);
                racc.x += ex * xls[j].x; racc.y += ex * xls[j].y;
                racc.z += ex * xls[j].z; racc.w += ex * xls[j].w;
                rden += ex;
            }
        }
        if (rkey >= 0) {
            float* p = out_acc + (size_t)rkey * 64 + t0;
            atomAddF(p + 0, racc.x); atomAddF(p + 1, racc.y);
            atomAddF(p + 2, racc.z); atomAddF(p + 3, racc.w);
            if ((l & 15) == 0) atomAddF(&denom[rkey], rden);
        }
    }

    if (ACC_LOOP) {
        // accumulate staged ea rows into loop_sum, run-combined by dst.
        const int kk = (l & 15) * 2;
        float a0 = 0.f, a1 = 0.f;
        int rkey = -1;
#pragma unroll
        for (int j = 0; j < 4; ++j) {
            const int d = dd[j];
            if (d != rkey) {
                if (rkey >= 0) {
                    atomAddF(&loop_sum[(size_t)rkey * 32 + kk], a0);
                    atomAddF(&loop_sum[(size_t)rkey * 32 + kk + 1], a1);
                }
                rkey = d; a0 = 0.f; a1 = 0.f;
            }
            if (rkey >= 0) {
                a0 += ea_T[kk][e0 + j];
                a1 += ea_T[kk + 1][e0 + j];
            }
        }
        if (rkey >= 0) {
            atomAddF(&loop_sum[(size_t)rkey * 32 + kk], a0);
            atomAddF(&loop_sum[(size_t)rkey * 32 + kk + 1], a1);
        }
    }
}

// ---------- loop_attr = loop_sum / max(deg,1) ----------
__global__ void k_loop_norm(const float* __restrict__ loop_sum, const int* __restrict__ deg,
                            float* __restrict__ loop_attr, int n) {
    int gid = blockIdx.x * 256 + threadIdx.x;
    if (gid >= n * 32) return;
    int i = gid >> 5;
    loop_attr[gid] = loop_sum[gid] / fmaxf((float)deg[i], 1.f);
}

// ---------- self-loop scores: ex_loop[i] = exp(att . leaky(xl_i+xr_i+We^T la_i)) ----------
__global__ __launch_bounds__(256) void k_loop_score(
    const float* __restrict__ xl, const float* __restrict__ xr,
    const float* __restrict__ loop_attr,
    const float* __restrict__ We, const float* __restrict__ att,
    int n, float* __restrict__ ex_loop) {
    __shared__ float We_s[32 * 64];
    __shared__ float ea_T[32][68];
    __shared__ float att_s[64];

    const int tid = threadIdx.x;
    const int ge0 = blockIdx.x * 64;

    for (int i = tid; i < 2048; i += 256) We_s[i] = We[i];
    if (tid < 64) att_s[tid] = att[tid];
    {
        int e = tid & 63;
        int k0 = (tid >> 6) * 8;
        int ge = ge0 + e;
        float4 a = make_float4(0.f, 0.f, 0.f, 0.f), b = a;
        if (ge < n) {
            const float4* p = (const float4*)(loop_attr + (size_t)ge * 32 + k0);
            a = p[0]; b = p[1];
        }
        ea_T[k0 + 0][e] = a.x; ea_T[k0 + 1][e] = a.y; ea_T[k0 + 2][e] = a.z; ea_T[k0 + 3][e] = a.w;
        ea_T[k0 + 4][e] = b.x; ea_T[k0 + 5][e] = b.y; ea_T[k0 + 6][e] = b.z; ea_T[k0 + 7][e] = b.w;
    }
    __syncthreads();

    const int w = tid >> 6, l = tid & 63;
    const int t0 = (l & 15) * 4;
    const int e0 = w * 16 + (l >> 4) * 4;

    float z[4][4];
#pragma unroll
    for (int j = 0; j < 4; ++j)
#pragma unroll
        for (int i = 0; i < 4; ++i) z[j][i] = 0.f;

#pragma unroll 8
    for (int k = 0; k < 32; ++k) {
        const float4 ev = *(const float4*)&ea_T[k][e0];
        const float4 wv = *(const float4*)&We_s[k * 64 + t0];
        const float ee[4] = {ev.x, ev.y, ev.z, ev.w};
        const float ww[4] = {wv.x, wv.y, wv.z, wv.w};
#pragma unroll
        for (int j = 0; j < 4; ++j)
#pragma unroll
            for (int i = 0; i < 4; ++i) z[j][i] += ee[j] * ww[i];
    }

    const float4 av = *(const float4*)&att_s[t0];
    const float aa[4] = {av.x, av.y, av.z, av.w};
    float v[4];
#pragma unroll
    for (int j = 0; j < 4; ++j) {
        const int node = ge0 + e0 + j;
        const int nsafe = (node < n) ? node : 0;
        const float4 xlv = *(const float4*)&xl[(size_t)nsafe * 64 + t0];
        const float4 xrv = *(const float4*)&xr[(size_t)nsafe * 64 + t0];
        const float xll[4] = {xlv.x, xlv.y, xlv.z, xlv.w};
        const float xrr[4] = {xrv.x, xrv.y, xrv.z, xrv.w};
        float acc = 0.f;
#pragma unroll
        for (int i = 0; i < 4; ++i) {
            float zz = z[j][i] + xll[i] + xrr[i];
            zz = (zz > 0.f) ? zz : NEG_SLOPE * zz;
            acc += aa[i] * zz;
        }
        v[j] = acc;
    }
#pragma unroll
    for (int m = 1; m < 16; m <<= 1) {
#pragma unroll
        for (int j = 0; j < 4; ++j) v[j] += __shfl_xor(v[j], m);
    }
    if ((l & 15) == 0) {
#pragma unroll
        for (int j = 0; j < 4; ++j) {
            int node = ge0 + e0 + j;
            if (node < n) ex_loop[node] = __expf(v[j]);
        }
    }
}

// ---------- epilogue: add self-loop, normalize, bias, relu (+classifier) ----------
template <bool FINAL>
__global__ __launch_bounds__(256) void k_finish(
    const float* __restrict__ out_acc, const float* __restrict__ denom,
    const float* __restrict__ ex_loop, const float* __restrict__ xl,
    const float* __restrict__ bias,
    const float* __restrict__ Wc, const float* __restrict__ bc,
    float* __restrict__ hout, int n) {
    int node = blockIdx.x * 4 + (threadIdx.x >> 6);
    int t = threadIdx.x & 63;
    if (node >= n) return;
    const float exl = ex_loop[node];
    const float den = denom[node] + exl;
    float v = (out_acc[(size_t)node * 64 + t] + exl * xl[(size_t)node * 64 + t]) / den + bias[t];
    float h = v > 0.f ? v : 0.f;
    if (!FINAL) {
        hout[(size_t)node * 64 + t] = h;
    } else {
        float v0 = h * Wc[t * 2 + 0];
        float v1 = h * Wc[t * 2 + 1];
#pragma unroll
        for (int m2 = 32; m2 >= 1; m2 >>= 1) {
            v0 += __shfl_xor(v0, m2);
            v1 += __shfl_xor(v1, m2);
        }
        if (t == 0) {
            hout[(size_t)node * 2 + 0] = v0 + bc[0];
            hout[(size_t)node * 2 + 1] = v1 + bc[1];
        }
    }
}

extern "C" void kernel_launch(void* const* d_in, const int* in_sizes, int n_in,
                              void* d_out, int out_size, void* d_ws, size_t ws_size,
                              hipStream_t stream) {
    const float* x     = (const float*)d_in[0];
    const int*   ei    = (const int*)d_in[1];
    const float* eattr = (const float*)d_in[2];
    const float* Wl1 = (const float*)d_in[3];
    const float* bl1 = (const float*)d_in[4];
    const float* Wr1 = (const float*)d_in[5];
    const float* br1 = (const float*)d_in[6];
    const float* We1 = (const float*)d_in[7];
    const float* att1 = (const float*)d_in[8];
    const float* bias1 = (const float*)d_in[9];
    const float* Wl2 = (const float*)d_in[10];
    const float* bl2 = (const float*)d_in[11];
    const float* Wr2 = (const float*)d_in[12];
    const float* br2 = (const float*)d_in[13];
    const float* We2 = (const float*)d_in[14];
    const float* att2 = (const float*)d_in[15];
    const float* bias2 = (const float*)d_in[16];
    const float* Wc = (const float*)d_in[17];
    const float* bc = (const float*)d_in[18];

    const int N = in_sizes[0] / 128;
    const int E = in_sizes[1] / 2;
    const int* src = ei;
    const int* dst = ei + E;

    char* w = (char*)d_ws;
    auto alloc = [&](size_t bytes) {
        char* p = w;
        w += (bytes + 255) & ~(size_t)255;
        return p;
    };
    float* xl         = (float*)alloc((size_t)N * 64 * 4);
    float* xr         = (float*)alloc((size_t)N * 64 * 4);
    float* hbuf       = (float*)alloc((size_t)N * 64 * 4);
    float* out_acc    = (float*)alloc((size_t)N * 64 * 4);
    float* loop_sum   = (float*)alloc((size_t)N * 32 * 4);
    float* loop_attr  = (float*)alloc((size_t)N * 32 * 4);
    float* ex_loop    = (float*)alloc((size_t)N * 4);
    float* denom      = (float*)alloc((size_t)N * 4);
    int*   deg_i      = (int*)alloc((size_t)N * 4);
    int*   start      = (int*)alloc((size_t)(N + 1) * 4);
    int*   cursor     = (int*)alloc((size_t)N * 4);
    int*   perm       = (int*)alloc((size_t)E * 4);
    int*   src_sorted = (int*)alloc((size_t)E * 4);
    int*   dst_sorted = (int*)alloc((size_t)E * 4);

    const int THREADS = 256;
    const int fused_blocks = (E + 63) / 64;
    const int loop_blocks = (N + 63) / 64;
    const int node4_blocks = (N + 3) / 4;
    const int edge_blocks = (E + THREADS - 1) / THREADS;

    // ---- CSR by dst (shared by both layers) ----
    hipMemsetAsync(deg_i, 0, (size_t)N * 4, stream);
    hipMemsetAsync(cursor, 0, (size_t)N * 4, stream);
    k_hist<<<edge_blocks, THREADS, 0, stream>>>(dst, E, deg_i);
    k_scan<<<1, 1024, 0, stream>>>(deg_i, start, N);
    k_fill<<<edge_blocks, THREADS, 0, stream>>>(src, dst, E, start, cursor,
                                                perm, src_sorted, dst_sorted);

    // ---- layer 1 (also accumulates loop_sum) ----
    k_node_transform<128><<<node4_blocks, THREADS, 0, stream>>>(x, Wl1, bl1, Wr1, br1, xl, xr, N);
    hipMemsetAsync(out_acc, 0, (size_t)N * 64 * 4, stream);
    hipMemsetAsync(denom, 0, (size_t)N * 4, stream);
    hipMemsetAsync(loop_sum, 0, (size_t)N * 32 * 4, stream);
    k_edge_fused<true><<<fused_blocks, THREADS, 0, stream>>>(
        xl, xr, eattr, We1, att1, perm, src_sorted, dst_sorted, E,
        denom, out_acc, loop_sum);
    {
        int blocks = (N * 32 + THREADS - 1) / THREADS;
        k_loop_norm<<<blocks, THREADS, 0, stream>>>(loop_sum, deg_i, loop_attr, N);
    }
    k_loop_score<<<loop_blocks, THREADS, 0, stream>>>(xl, xr, loop_attr, We1, att1, N, ex_loop);
    k_finish<false><<<node4_blocks, THREADS, 0, stream>>>(out_acc, denom, ex_loop, xl,
                                                          bias1, Wc, bc, hbuf, N);

    // ---- layer 2 ----
    k_node_transform<64><<<node4_blocks, THREADS, 0, stream>>>(hbuf, Wl2, bl2, Wr2, br2, xl, xr, N);
    hipMemsetAsync(out_acc, 0, (size_t)N * 64 * 4, stream);
    hipMemsetAsync(denom, 0, (size_t)N * 4, stream);
    k_loop_score<<<loop_blocks, THREADS, 0, stream>>>(xl, xr, loop_attr, We2, att2, N, ex_loop);
    k_edge_fused<false><<<fused_blocks, THREADS, 0, stream>>>(
        xl, xr, eattr, We2, att2, perm, src_sorted, dst_sorted, E,
        denom, out_acc, loop_sum);
    k_finish<true><<<node4_blocks, THREADS, 0, stream>>>(out_acc, denom, ex_loop, xl,
                                                         bias2, Wc, bc, (float*)d_out, N);
}

// Round 6
// 1111.272 us; speedup vs baseline: 1.6253x; 1.6253x over previous
//
#include <hip/hip_runtime.h>
#include <hip/hip_bf16.h>

#define NEG_SLOPE 0.2f

__device__ __forceinline__ void atomAddF(float* p, float v) {
    unsafeAtomicAdd(p, v);   // hardware global_atomic_add_f32 on gfx950
}

// ---------- CSR build ----------
__global__ void k_hist(const int* __restrict__ dst, int E, int* __restrict__ deg) {
    int e = blockIdx.x * 256 + threadIdx.x;
    if (e < E) atomicAdd(&deg[dst[e]], 1);
}

__global__ __launch_bounds__(1024) void k_scan(const int* __restrict__ deg,
                                               int* __restrict__ start, int n) {
    __shared__ int wsum[16];
    __shared__ int carry_s;
    if (threadIdx.x == 0) carry_s = 0;
    __syncthreads();
    const int lane = threadIdx.x & 63;
    const int w = threadIdx.x >> 6;
    for (int base = 0; base < n; base += 1024) {
        int i = base + (int)threadIdx.x;
        int v = (i < n) ? deg[i] : 0;
        int s = v;
#pragma unroll
        for (int o = 1; o < 64; o <<= 1) {
            int u = __shfl_up(s, o);
            if (lane >= o) s += u;
        }
        if (lane == 63) wsum[w] = s;
        __syncthreads();
        if (w == 0) {
            int ws = (lane < 16) ? wsum[lane] : 0;
#pragma unroll
            for (int o = 1; o < 16; o <<= 1) {
                int u = __shfl_up(ws, o);
                if (lane >= o) ws += u;
            }
            if (lane < 16) wsum[lane] = ws;
        }
        __syncthreads();
        int carry = carry_s;
        int woff = (w == 0) ? 0 : wsum[w - 1];
        int incl = s + woff + carry;
        if (i < n) start[i] = incl - v;
        __syncthreads();
        if (threadIdx.x == 1023) carry_s = incl;
        __syncthreads();
    }
    if (threadIdx.x == 0) start[n] = carry_s;
}

__global__ void k_fill(const int* __restrict__ src, const int* __restrict__ dst, int E,
                       const int* __restrict__ start, int* __restrict__ cursor,
                       int* __restrict__ perm, int* __restrict__ src_sorted,
                       int* __restrict__ dst_sorted) {
    int e = blockIdx.x * 256 + threadIdx.x;
    if (e >= E) return;
    int d = dst[e];
    int idx = start[d] + atomicAdd(&cursor[d], 1);
    perm[idx] = e;
    src_sorted[idx] = src[e];
    dst_sorted[idx] = d;
}

// ---------- self-loop attr: gather-side segment mean ----------
__global__ __launch_bounds__(256) void k_loop_csr(
    const float* __restrict__ eattr, const int* __restrict__ perm,
    const int* __restrict__ start, float* __restrict__ loop_attr, int n) {
    int node = blockIdx.x * 4 + (threadIdx.x >> 6);
    int t = threadIdx.x & 63;
    if (node >= n) return;
    int a = start[node], b = start[node + 1];
    int g = t >> 3, gl = t & 7;
    float4 acc = make_float4(0.f, 0.f, 0.f, 0.f);
    for (int j = a + g; j < b; j += 8) {
        int e = perm[j];
        const float4 v = *(const float4*)&eattr[(size_t)e * 32 + gl * 4];
        acc.x += v.x; acc.y += v.y; acc.z += v.z; acc.w += v.w;
    }
#pragma unroll
    for (int mask = 8; mask <= 32; mask <<= 1) {
        acc.x += __shfl_xor(acc.x, mask);
        acc.y += __shfl_xor(acc.y, mask);
        acc.z += __shfl_xor(acc.z, mask);
        acc.w += __shfl_xor(acc.w, mask);
    }
    if (t < 8) {
        float deg = fmaxf((float)(b - a), 1.f);
        float4 o = make_float4(acc.x / deg, acc.y / deg, acc.z / deg, acc.w / deg);
        *(float4*)&loop_attr[(size_t)node * 32 + gl * 4] = o;
    }
}

// ---------- node transform: xl = h@Wl+bl, xr = h@Wr+br ----------
template <int DIN>
__global__ void k_node_transform(const float* __restrict__ h,
                                 const float* __restrict__ Wl, const float* __restrict__ bl,
                                 const float* __restrict__ Wr, const float* __restrict__ br,
                                 float* __restrict__ xl, float* __restrict__ xr, int n) {
    __shared__ float hs[4][DIN];
    int node0 = blockIdx.x * 4;
    int tid = threadIdx.x;
    for (int idx = tid; idx < 4 * DIN; idx += 256) {
        int ln = idx / DIN, k = idx % DIN;
        int node = node0 + ln;
        hs[ln][k] = (node < n) ? h[(long long)node * DIN + k] : 0.f;
    }
    __syncthreads();
    int ln = tid >> 6;
    int j = tid & 63;
    int node = node0 + ln;
    if (node >= n) return;
    float al = bl[j], ar = br[j];
#pragma unroll 8
    for (int k = 0; k < DIN; ++k) {
        float hv = hs[ln][k];
        al += hv * Wl[k * 64 + j];
        ar += hv * Wr[k * 64 + j];
    }
    xl[(long long)node * 64 + j] = al;
    xr[(long long)node * 64 + j] = ar;
}

// ---------- mega edge pass over dst-SORTED edges ----------
// 64 edges/block: GEMM tile -> score -> exp -> register run-combine ->
// LDS segmented reduction keyed by d_local -> ONE global atomic flush per
// distinct dst per block (~3/block).
__global__ __launch_bounds__(256) void k_mega(
    const float* __restrict__ xl, const float* __restrict__ xr,
    const float* __restrict__ eattr,
    const float* __restrict__ We, const float* __restrict__ att,
    const int* __restrict__ perm, const int* __restrict__ src_sorted,
    const int* __restrict__ dst_sorted, int E,
    float* __restrict__ denom, float* __restrict__ out_acc) {
    __shared__ float We_s[32 * 64];
    __shared__ float ea_T[32][68];
    __shared__ float att_s[64];
    __shared__ int s_s[64], d_s[64], d_loc[64];
    __shared__ float accum[64][65];
    __shared__ float den_s[64];

    const int tid = threadIdx.x;
    const int ge0 = blockIdx.x * 64;

    for (int i = tid; i < 2048; i += 256) We_s[i] = We[i];
    if (tid < 64) att_s[tid] = att[tid];
    if (tid >= 64 && tid < 128) {
        int eb = tid - 64, ge = ge0 + eb;
        s_s[eb] = (ge < E) ? src_sorted[ge] : 0;
    }
    if (tid >= 128 && tid < 192) {
        int eb = tid - 128, ge = ge0 + eb;
        d_s[eb] = (ge < E) ? dst_sorted[ge] : -1;
    }
    for (int i = tid; i < 64 * 65; i += 256) ((float*)accum)[i] = 0.f;
    if (tid < 64) den_s[tid] = 0.f;
    {
        int e = tid & 63;          // lane varies along e -> conflict-free banks
        int k0 = (tid >> 6) * 8;   // wave-uniform k chunk
        int ge = ge0 + e;
        float4 a = make_float4(0.f, 0.f, 0.f, 0.f), b = a;
        if (ge < E) {
            int pe = perm[ge];
            const float4* p = (const float4*)(eattr + (size_t)pe * 32 + k0);
            a = p[0]; b = p[1];
        }
        ea_T[k0 + 0][e] = a.x; ea_T[k0 + 1][e] = a.y; ea_T[k0 + 2][e] = a.z; ea_T[k0 + 3][e] = a.w;
        ea_T[k0 + 4][e] = b.x; ea_T[k0 + 5][e] = b.y; ea_T[k0 + 6][e] = b.z; ea_T[k0 + 7][e] = b.w;
    }
    __syncthreads();

    const int w = tid >> 6, l = tid & 63;

    // wave 0: d_local = index of first edge in block with same dst (shfl max-scan)
    if (w == 0) {
        int dval = d_s[l];
        int head = (l == 0) || (d_s[l - 1] != dval);
        int idx = head ? l : 0;
#pragma unroll
        for (int o = 1; o < 64; o <<= 1) {
            int u = __shfl_up(idx, o);
            if (l >= o && u > idx) idx = u;
        }
        d_loc[l] = idx;
    }

    const int t0 = (l & 15) * 4;            // channel group
    const int e0 = w * 16 + (l >> 4) * 4;   // edge group (4 sorted edges)

    float z[4][4];
#pragma unroll
    for (int j = 0; j < 4; ++j)
#pragma unroll
        for (int i = 0; i < 4; ++i) z[j][i] = 0.f;

#pragma unroll 8
    for (int k = 0; k < 32; ++k) {
        const float4 ev = *(const float4*)&ea_T[k][e0];
        const float4 wv = *(const float4*)&We_s[k * 64 + t0];
        const float ee[4] = {ev.x, ev.y, ev.z, ev.w};
        const float ww[4] = {wv.x, wv.y, wv.z, wv.w};
#pragma unroll
        for (int j = 0; j < 4; ++j)
#pragma unroll
            for (int i = 0; i < 4; ++i) z[j][i] += ee[j] * ww[i];
    }

    const float4 av = *(const float4*)&att_s[t0];
    const float aa[4] = {av.x, av.y, av.z, av.w};
    float v[4];
    float4 xls[4];
    int dd[4];
#pragma unroll
    for (int j = 0; j < 4; ++j) {
        const int eb = e0 + j;
        const int s = s_s[eb];
        dd[j] = d_s[eb];
        const int dsafe = (dd[j] >= 0) ? dd[j] : 0;
        const float4 xlv = *(const float4*)&xl[(size_t)s * 64 + t0];
        const float4 xrv = *(const float4*)&xr[(size_t)dsafe * 64 + t0];
        xls[j] = xlv;
        const float xll[4] = {xlv.x, xlv.y, xlv.z, xlv.w};
        const float xrr[4] = {xrv.x, xrv.y, xrv.z, xrv.w};
        float acc = 0.f;
#pragma unroll
        for (int i = 0; i < 4; ++i) {
            float zz = z[j][i] + xll[i] + xrr[i];
            zz = (zz > 0.f) ? zz : NEG_SLOPE * zz;
            acc += aa[i] * zz;
        }
        v[j] = acc;
    }
#pragma unroll
    for (int m = 1; m < 16; m <<= 1) {
#pragma unroll
        for (int j = 0; j < 4; ++j) v[j] += __shfl_xor(v[j], m);
    }
    __syncthreads();   // d_loc visible; accum zero (done pre-sync1)

    // register run-combine -> LDS segmented accumulation
    {
        float4 racc = make_float4(0.f, 0.f, 0.f, 0.f);
        float rden = 0.f;
        int rloc = -1;
        bool rvalid = false;
#pragma unroll
        for (int j = 0; j < 4; ++j) {
            const int eb = e0 + j;
            const int loc = d_loc[eb];
            if (loc != rloc) {
                if (rvalid) {
                    atomicAdd(&accum[rloc][t0 + 0], racc.x);
                    atomicAdd(&accum[rloc][t0 + 1], racc.y);
                    atomicAdd(&accum[rloc][t0 + 2], racc.z);
                    atomicAdd(&accum[rloc][t0 + 3], racc.w);
                    if ((l & 15) == 0) atomicAdd(&den_s[rloc], rden);
                }
                rloc = loc;
                racc = make_float4(0.f, 0.f, 0.f, 0.f);
                rden = 0.f;
                rvalid = false;
            }
            if (dd[j] >= 0) {
                const float ex = __expf(v[j]);
                racc.x += ex * xls[j].x; racc.y += ex * xls[j].y;
                racc.z += ex * xls[j].z; racc.w += ex * xls[j].w;
                rden += ex;
                rvalid = true;
            }
        }
        if (rvalid) {
            atomicAdd(&accum[rloc][t0 + 0], racc.x);
            atomicAdd(&accum[rloc][t0 + 1], racc.y);
            atomicAdd(&accum[rloc][t0 + 2], racc.z);
            atomicAdd(&accum[rloc][t0 + 3], racc.w);
            if ((l & 15) == 0) atomicAdd(&den_s[rloc], rden);
        }
    }
    __syncthreads();

    // flush: one global atomic row-add per distinct dst in block
#pragma unroll
    for (int j = 0; j < 4; ++j) {
        const int eb = e0 + j;
        const int d = d_s[eb];
        if (d >= 0 && d_loc[eb] == eb) {
            float* p = out_acc + (size_t)d * 64 + t0;
            atomAddF(p + 0, accum[eb][t0 + 0]);
            atomAddF(p + 1, accum[eb][t0 + 1]);
            atomAddF(p + 2, accum[eb][t0 + 2]);
            atomAddF(p + 3, accum[eb][t0 + 3]);
            if ((l & 15) == 0) atomAddF(&denom[d], den_s[eb]);
        }
    }
}

// ---------- self-loop scores ----------
__global__ __launch_bounds__(256) void k_loop_score(
    const float* __restrict__ xl, const float* __restrict__ xr,
    const float* __restrict__ loop_attr,
    const float* __restrict__ We, const float* __restrict__ att,
    int n, float* __restrict__ ex_loop) {
    __shared__ float We_s[32 * 64];
    __shared__ float ea_T[32][68];
    __shared__ float att_s[64];

    const int tid = threadIdx.x;
    const int ge0 = blockIdx.x * 64;

    for (int i = tid; i < 2048; i += 256) We_s[i] = We[i];
    if (tid < 64) att_s[tid] = att[tid];
    {
        int e = tid & 63;
        int k0 = (tid >> 6) * 8;
        int ge = ge0 + e;
        float4 a = make_float4(0.f, 0.f, 0.f, 0.f), b = a;
        if (ge < n) {
            const float4* p = (const float4*)(loop_attr + (size_t)ge * 32 + k0);
            a = p[0]; b = p[1];
        }
        ea_T[k0 + 0][e] = a.x; ea_T[k0 + 1][e] = a.y; ea_T[k0 + 2][e] = a.z; ea_T[k0 + 3][e] = a.w;
        ea_T[k0 + 4][e] = b.x; ea_T[k0 + 5][e] = b.y; ea_T[k0 + 6][e] = b.z; ea_T[k0 + 7][e] = b.w;
    }
    __syncthreads();

    const int w = tid >> 6, l = tid & 63;
    const int t0 = (l & 15) * 4;
    const int e0 = w * 16 + (l >> 4) * 4;

    float z[4][4];
#pragma unroll
    for (int j = 0; j < 4; ++j)
#pragma unroll
        for (int i = 0; i < 4; ++i) z[j][i] = 0.f;

#pragma unroll 8
    for (int k = 0; k < 32; ++k) {
        const float4 ev = *(const float4*)&ea_T[k][e0];
        const float4 wv = *(const float4*)&We_s[k * 64 + t0];
        const float ee[4] = {ev.x, ev.y, ev.z, ev.w};
        const float ww[4] = {wv.x, wv.y, wv.z, wv.w};
#pragma unroll
        for (int j = 0; j < 4; ++j)
#pragma unroll
            for (int i = 0; i < 4; ++i) z[j][i] += ee[j] * ww[i];
    }

    const float4 av = *(const float4*)&att_s[t0];
    const float aa[4] = {av.x, av.y, av.z, av.w};
    float v[4];
#pragma unroll
    for (int j = 0; j < 4; ++j) {
        const int node = ge0 + e0 + j;
        const int nsafe = (node < n) ? node : 0;
        const float4 xlv = *(const float4*)&xl[(size_t)nsafe * 64 + t0];
        const float4 xrv = *(const float4*)&xr[(size_t)nsafe * 64 + t0];
        const float xll[4] = {xlv.x, xlv.y, xlv.z, xlv.w};
        const float xrr[4] = {xrv.x, xrv.y, xrv.z, xrv.w};
        float acc = 0.f;
#pragma unroll
        for (int i = 0; i < 4; ++i) {
            float zz = z[j][i] + xll[i] + xrr[i];
            zz = (zz > 0.f) ? zz : NEG_SLOPE * zz;
            acc += aa[i] * zz;
        }
        v[j] = acc;
    }
#pragma unroll
    for (int m = 1; m < 16; m <<= 1) {
#pragma unroll
        for (int j = 0; j < 4; ++j) v[j] += __shfl_xor(v[j], m);
    }
    if ((l & 15) == 0) {
#pragma unroll
        for (int j = 0; j < 4; ++j) {
            int node = ge0 + e0 + j;
            if (node < n) ex_loop[node] = __expf(v[j]);
        }
    }
}

// ---------- epilogue: add self-loop, normalize, bias, relu (+classifier) ----------
template <bool FINAL>
__global__ __launch_bounds__(256) void k_finish(
    const float* __restrict__ out_acc, const float* __restrict__ denom,
    const float* __restrict__ ex_loop, const float* __restrict__ xl,
    const float* __restrict__ bias,
    const float* __restrict__ Wc, const float* __restrict__ bc,
    float* __restrict__ hout, int n) {
    int node = blockIdx.x * 4 + (threadIdx.x >> 6);
    int t = threadIdx.x & 63;
    if (node >= n) return;
    const float exl = ex_loop[node];
    const float den = denom[node] + exl;
    float v = (out_acc[(size_t)node * 64 + t] + exl * xl[(size_t)node * 64 + t]) / den + bias[t];
    float h = v > 0.f ? v : 0.f;
    if (!FINAL) {
        hout[(size_t)node * 64 + t] = h;
    } else {
        float v0 = h * Wc[t * 2 + 0];
        float v1 = h * Wc[t * 2 + 1];
#pragma unroll
        for (int m2 = 32; m2 >= 1; m2 >>= 1) {
            v0 += __shfl_xor(v0, m2);
            v1 += __shfl_xor(v1, m2);
        }
        if (t == 0) {
            hout[(size_t)node * 2 + 0] = v0 + bc[0];
            hout[(size_t)node * 2 + 1] = v1 + bc[1];
        }
    }
}

extern "C" void kernel_launch(void* const* d_in, const int* in_sizes, int n_in,
                              void* d_out, int out_size, void* d_ws, size_t ws_size,
                              hipStream_t stream) {
    const float* x     = (const float*)d_in[0];
    const int*   ei    = (const int*)d_in[1];
    const float* eattr = (const float*)d_in[2];
    const float* Wl1 = (const float*)d_in[3];
    const float* bl1 = (const float*)d_in[4];
    const float* Wr1 = (const float*)d_in[5];
    const float* br1 = (const float*)d_in[6];
    const float* We1 = (const float*)d_in[7];
    const float* att1 = (const float*)d_in[8];
    const float* bias1 = (const float*)d_in[9];
    const float* Wl2 = (const float*)d_in[10];
    const float* bl2 = (const float*)d_in[11];
    const float* Wr2 = (const float*)d_in[12];
    const float* br2 = (const float*)d_in[13];
    const float* We2 = (const float*)d_in[14];
    const float* att2 = (const float*)d_in[15];
    const float* bias2 = (const float*)d_in[16];
    const float* Wc = (const float*)d_in[17];
    const float* bc = (const float*)d_in[18];

    const int N = in_sizes[0] / 128;
    const int E = in_sizes[1] / 2;
    const int* src = ei;
    const int* dst = ei + E;

    char* w = (char*)d_ws;
    auto alloc = [&](size_t bytes) {
        char* p = w;
        w += (bytes + 255) & ~(size_t)255;
        return p;
    };
    float* xl         = (float*)alloc((size_t)N * 64 * 4);
    float* xr         = (float*)alloc((size_t)N * 64 * 4);
    float* hbuf       = (float*)alloc((size_t)N * 64 * 4);
    float* out_acc    = (float*)alloc((size_t)N * 64 * 4);
    float* loop_attr  = (float*)alloc((size_t)N * 32 * 4);
    float* ex_loop    = (float*)alloc((size_t)N * 4);
    float* denom      = (float*)alloc((size_t)N * 4);
    int*   deg_i      = (int*)alloc((size_t)N * 4);
    int*   start      = (int*)alloc((size_t)(N + 1) * 4);
    int*   cursor     = (int*)alloc((size_t)N * 4);
    int*   perm       = (int*)alloc((size_t)E * 4);
    int*   src_sorted = (int*)alloc((size_t)E * 4);
    int*   dst_sorted = (int*)alloc((size_t)E * 4);

    const int THREADS = 256;
    const int mega_blocks = (E + 63) / 64;
    const int loop_blocks = (N + 63) / 64;
    const int node4_blocks = (N + 3) / 4;
    const int edge_blocks = (E + THREADS - 1) / THREADS;

    // ---- CSR by dst (shared by both layers) ----
    hipMemsetAsync(deg_i, 0, (size_t)N * 4, stream);
    hipMemsetAsync(cursor, 0, (size_t)N * 4, stream);
    k_hist<<<edge_blocks, THREADS, 0, stream>>>(dst, E, deg_i);
    k_scan<<<1, 1024, 0, stream>>>(deg_i, start, N);
    k_fill<<<edge_blocks, THREADS, 0, stream>>>(src, dst, E, start, cursor,
                                                perm, src_sorted, dst_sorted);
    k_loop_csr<<<node4_blocks, THREADS, 0, stream>>>(eattr, perm, start, loop_attr, N);

    // ---- layer 1 ----
    k_node_transform<128><<<node4_blocks, THREADS, 0, stream>>>(x, Wl1, bl1, Wr1, br1, xl, xr, N);
    hipMemsetAsync(out_acc, 0, (size_t)N * 64 * 4, stream);
    hipMemsetAsync(denom, 0, (size_t)N * 4, stream);
    k_mega<<<mega_blocks, THREADS, 0, stream>>>(xl, xr, eattr, We1, att1,
                                                perm, src_sorted, dst_sorted, E,
                                                denom, out_acc);
    k_loop_score<<<loop_blocks, THREADS, 0, stream>>>(xl, xr, loop_attr, We1, att1, N, ex_loop);
    k_finish<false><<<node4_blocks, THREADS, 0, stream>>>(out_acc, denom, ex_loop, xl,
                                                          bias1, Wc, bc, hbuf, N);

    // ---- layer 2 ----
    k_node_transform<64><<<node4_blocks, THREADS, 0, stream>>>(hbuf, Wl2, bl2, Wr2, br2, xl, xr, N);
    hipMemsetAsync(out_acc, 0, (size_t)N * 64 * 4, stream);
    hipMemsetAsync(denom, 0, (size_t)N * 4, stream);
    k_mega<<<mega_blocks, THREADS, 0, stream>>>(xl, xr, eattr, We2, att2,
                                                perm, src_sorted, dst_sorted, E,
                                                denom, out_acc);
    k_loop_score<<<loop_blocks, THREADS, 0, stream>>>(xl, xr, loop_attr, We2, att2, N, ex_loop);
    k_finish<true><<<node4_blocks, THREADS, 0, stream>>>(out_acc, denom, ex_loop, xl,
                                                         bias2, Wc, bc, (float*)d_out, N);
}

// Round 7
// 929.114 us; speedup vs baseline: 1.9439x; 1.1961x over previous
//
#include <hip/hip_runtime.h>
#include <hip/hip_bf16.h>

#define NEG_SLOPE 0.2f

__device__ __forceinline__ void atomAddF(float* p, float v) {
    unsafeAtomicAdd(p, v);   // hardware global_atomic_add_f32 on gfx950
}

// packed fp32 FMA, broadcasting LO or HI half of b across both lanes (VOP3P op_sel)
__device__ __forceinline__ float2 pk_fma_lo(float2 a, float2 b, float2 c) {
    float2 d;
    asm("v_pk_fma_f32 %0, %1, %2, %3 op_sel:[0,0,0] op_sel_hi:[1,0,1]"
        : "=v"(d) : "v"(a), "v"(b), "v"(c));
    return d;
}
__device__ __forceinline__ float2 pk_fma_hi(float2 a, float2 b, float2 c) {
    float2 d;
    asm("v_pk_fma_f32 %0, %1, %2, %3 op_sel:[0,1,0] op_sel_hi:[1,1,1]"
        : "=v"(d) : "v"(a), "v"(b), "v"(c));
    return d;
}

// ---------- CSR build ----------
__global__ void k_hist(const int* __restrict__ dst, int E, int* __restrict__ deg) {
    int e = blockIdx.x * 256 + threadIdx.x;
    if (e < E) atomicAdd(&deg[dst[e]], 1);
}

__global__ __launch_bounds__(1024) void k_scan(const int* __restrict__ deg,
                                               int* __restrict__ start, int n) {
    __shared__ int wsum[16];
    __shared__ int carry_s;
    if (threadIdx.x == 0) carry_s = 0;
    __syncthreads();
    const int lane = threadIdx.x & 63;
    const int w = threadIdx.x >> 6;
    for (int base = 0; base < n; base += 1024) {
        int i = base + (int)threadIdx.x;
        int v = (i < n) ? deg[i] : 0;
        int s = v;
#pragma unroll
        for (int o = 1; o < 64; o <<= 1) {
            int u = __shfl_up(s, o);
            if (lane >= o) s += u;
        }
        if (lane == 63) wsum[w] = s;
        __syncthreads();
        if (w == 0) {
            int ws = (lane < 16) ? wsum[lane] : 0;
#pragma unroll
            for (int o = 1; o < 16; o <<= 1) {
                int u = __shfl_up(ws, o);
                if (lane >= o) ws += u;
            }
            if (lane < 16) wsum[lane] = ws;
        }
        __syncthreads();
        int carry = carry_s;
        int woff = (w == 0) ? 0 : wsum[w - 1];
        int incl = s + woff + carry;
        if (i < n) start[i] = incl - v;
        __syncthreads();
        if (threadIdx.x == 1023) carry_s = incl;
        __syncthreads();
    }
    if (threadIdx.x == 0) start[n] = carry_s;
}

__global__ void k_fill(const int* __restrict__ src, const int* __restrict__ dst, int E,
                       const int* __restrict__ start, int* __restrict__ cursor,
                       int* __restrict__ perm, int* __restrict__ src_sorted,
                       int* __restrict__ dst_sorted) {
    int e = blockIdx.x * 256 + threadIdx.x;
    if (e >= E) return;
    int d = dst[e];
    int idx = start[d] + atomicAdd(&cursor[d], 1);
    perm[idx] = e;
    src_sorted[idx] = src[e];
    dst_sorted[idx] = d;
}

// ---------- node transform: xl = h@Wl+bl, xr = h@Wr+br ----------
template <int DIN>
__global__ void k_node_transform(const float* __restrict__ h,
                                 const float* __restrict__ Wl, const float* __restrict__ bl,
                                 const float* __restrict__ Wr, const float* __restrict__ br,
                                 float* __restrict__ xl, float* __restrict__ xr, int n) {
    __shared__ float hs[4][DIN];
    int node0 = blockIdx.x * 4;
    int tid = threadIdx.x;
    for (int idx = tid; idx < 4 * DIN; idx += 256) {
        int ln = idx / DIN, k = idx % DIN;
        int node = node0 + ln;
        hs[ln][k] = (node < n) ? h[(long long)node * DIN + k] : 0.f;
    }
    __syncthreads();
    int ln = tid >> 6;
    int j = tid & 63;
    int node = node0 + ln;
    if (node >= n) return;
    float al = bl[j], ar = br[j];
#pragma unroll 8
    for (int k = 0; k < DIN; ++k) {
        float hv = hs[ln][k];
        al += hv * Wl[k * 64 + j];
        ar += hv * Wr[k * 64 + j];
    }
    xl[(long long)node * 64 + j] = al;
    xr[(long long)node * 64 + j] = ar;
}

// ---------- phase A: edge scores over dst-SORTED edges -> ex_sorted ----------
// 64 sorted edges/block; pk_fma GEMM tile; xr[dst] L1-cached by sortedness;
// coalesced ex write. ACC_LOOP: run-combined loop_sum accumulation from the
// staged ea tile (replaces a third full eattr pass).
template <bool ACC_LOOP>
__global__ __launch_bounds__(256) void k_edge_score(
    const float* __restrict__ xl, const float* __restrict__ xr,
    const float* __restrict__ eattr,
    const float* __restrict__ We, const float* __restrict__ att,
    const int* __restrict__ perm, const int* __restrict__ src_sorted,
    const int* __restrict__ dst_sorted, int E,
    float* __restrict__ ex_sorted, float* __restrict__ loop_sum) {
    __shared__ float We_s[32 * 64];
    __shared__ float ea_T[32][68];
    __shared__ float att_s[64];
    __shared__ int s_s[64], d_s[64];

    const int tid = threadIdx.x;
    const int ge0 = blockIdx.x * 64;

    for (int i = tid; i < 2048; i += 256) We_s[i] = We[i];
    if (tid < 64) att_s[tid] = att[tid];
    if (tid >= 64 && tid < 128) {
        int eb = tid - 64, ge = ge0 + eb;
        s_s[eb] = (ge < E) ? src_sorted[ge] : 0;
    }
    if (tid >= 128 && tid < 192) {
        int eb = tid - 128, ge = ge0 + eb;
        d_s[eb] = (ge < E) ? dst_sorted[ge] : -1;
    }
    {
        int e = tid & 63;          // lane varies along e -> conflict-free banks
        int k0 = (tid >> 6) * 8;   // wave-uniform k chunk
        int ge = ge0 + e;
        float4 a = make_float4(0.f, 0.f, 0.f, 0.f), b = a;
        if (ge < E) {
            int pe = perm[ge];
            const float4* p = (const float4*)(eattr + (size_t)pe * 32 + k0);
            a = p[0]; b = p[1];
        }
        ea_T[k0 + 0][e] = a.x; ea_T[k0 + 1][e] = a.y; ea_T[k0 + 2][e] = a.z; ea_T[k0 + 3][e] = a.w;
        ea_T[k0 + 4][e] = b.x; ea_T[k0 + 5][e] = b.y; ea_T[k0 + 6][e] = b.z; ea_T[k0 + 7][e] = b.w;
    }
    __syncthreads();

    const int w = tid >> 6, l = tid & 63;
    const int t0 = (l & 15) * 4;            // channel group
    const int e0 = w * 16 + (l >> 4) * 4;   // edge group (4 sorted edges)

    // zp[edge-pair][channel]: .x = even edge, .y = odd edge
    float2 zp[2][4];
#pragma unroll
    for (int p = 0; p < 2; ++p)
#pragma unroll
        for (int i = 0; i < 4; ++i) zp[p][i] = make_float2(0.f, 0.f);

#pragma unroll 8
    for (int k = 0; k < 32; ++k) {
        const float4 ev = *(const float4*)&ea_T[k][e0];
        const float4 wv = *(const float4*)&We_s[k * 64 + t0];
        const float2 ep0 = make_float2(ev.x, ev.y);
        const float2 ep1 = make_float2(ev.z, ev.w);
        const float2 wp0 = make_float2(wv.x, wv.y);
        const float2 wp1 = make_float2(wv.z, wv.w);
        zp[0][0] = pk_fma_lo(ep0, wp0, zp[0][0]);
        zp[0][1] = pk_fma_hi(ep0, wp0, zp[0][1]);
        zp[0][2] = pk_fma_lo(ep0, wp1, zp[0][2]);
        zp[0][3] = pk_fma_hi(ep0, wp1, zp[0][3]);
        zp[1][0] = pk_fma_lo(ep1, wp0, zp[1][0]);
        zp[1][1] = pk_fma_hi(ep1, wp0, zp[1][1]);
        zp[1][2] = pk_fma_lo(ep1, wp1, zp[1][2]);
        zp[1][3] = pk_fma_hi(ep1, wp1, zp[1][3]);
    }

    const float4 av = *(const float4*)&att_s[t0];
    const float aa[4] = {av.x, av.y, av.z, av.w};
    float v[4];
    int dd[4];
#pragma unroll
    for (int j = 0; j < 4; ++j) {
        const int eb = e0 + j;
        const int s = s_s[eb];
        dd[j] = d_s[eb];
        const int dsafe = (dd[j] >= 0) ? dd[j] : 0;
        const float4 xlv = *(const float4*)&xl[(size_t)s * 64 + t0];
        const float4 xrv = *(const float4*)&xr[(size_t)dsafe * 64 + t0];
        const float xll[4] = {xlv.x, xlv.y, xlv.z, xlv.w};
        const float xrr[4] = {xrv.x, xrv.y, xrv.z, xrv.w};
        const int p = j >> 1;
        float zj[4];
        if (j & 1) { zj[0] = zp[p][0].y; zj[1] = zp[p][1].y; zj[2] = zp[p][2].y; zj[3] = zp[p][3].y; }
        else       { zj[0] = zp[p][0].x; zj[1] = zp[p][1].x; zj[2] = zp[p][2].x; zj[3] = zp[p][3].x; }
        float acc = 0.f;
#pragma unroll
        for (int i = 0; i < 4; ++i) {
            float zz = zj[i] + xll[i] + xrr[i];
            zz = (zz > 0.f) ? zz : NEG_SLOPE * zz;
            acc += aa[i] * zz;
        }
        v[j] = acc;
    }
#pragma unroll
    for (int m = 1; m < 16; m <<= 1) {
#pragma unroll
        for (int j = 0; j < 4; ++j) v[j] += __shfl_xor(v[j], m);
    }
    if ((l & 15) == 0) {
#pragma unroll
        for (int j = 0; j < 4; ++j) {
            int ge = ge0 + e0 + j;
            if (ge < E) ex_sorted[ge] = __expf(v[j]);
        }
    }

    if (ACC_LOOP) {
        // accumulate staged ea rows into loop_sum, run-combined by dst.
        const int kk = (l & 15) * 2;
        float a0 = 0.f, a1 = 0.f;
        int rkey = -1;
#pragma unroll
        for (int j = 0; j < 4; ++j) {
            const int d = dd[j];
            if (d != rkey) {
                if (rkey >= 0) {
                    atomAddF(&loop_sum[(size_t)rkey * 32 + kk], a0);
                    atomAddF(&loop_sum[(size_t)rkey * 32 + kk + 1], a1);
                }
                rkey = d; a0 = 0.f; a1 = 0.f;
            }
            if (rkey >= 0) {
                a0 += ea_T[kk][e0 + j];
                a1 += ea_T[kk + 1][e0 + j];
            }
        }
        if (rkey >= 0) {
            atomAddF(&loop_sum[(size_t)rkey * 32 + kk], a0);
            atomAddF(&loop_sum[(size_t)rkey * 32 + kk + 1], a1);
        }
    }
}

// ---------- loop_attr = loop_sum / max(deg,1) ----------
__global__ void k_loop_norm(const float* __restrict__ loop_sum, const int* __restrict__ deg,
                            float* __restrict__ loop_attr, int n) {
    int gid = blockIdx.x * 256 + threadIdx.x;
    if (gid >= n * 32) return;
    int i = gid >> 5;
    loop_attr[gid] = loop_sum[gid] / fmaxf((float)deg[i], 1.f);
}

// ---------- self-loop scores ----------
__global__ __launch_bounds__(256) void k_loop_score(
    const float* __restrict__ xl, const float* __restrict__ xr,
    const float* __restrict__ loop_attr,
    const float* __restrict__ We, const float* __restrict__ att,
    int n, float* __restrict__ ex_loop) {
    __shared__ float We_s[32 * 64];
    __shared__ float ea_T[32][68];
    __shared__ float att_s[64];

    const int tid = threadIdx.x;
    const int ge0 = blockIdx.x * 64;

    for (int i = tid; i < 2048; i += 256) We_s[i] = We[i];
    if (tid < 64) att_s[tid] = att[tid];
    {
        int e = tid & 63;
        int k0 = (tid >> 6) * 8;
        int ge = ge0 + e;
        float4 a = make_float4(0.f, 0.f, 0.f, 0.f), b = a;
        if (ge < n) {
            const float4* p = (const float4*)(loop_attr + (size_t)ge * 32 + k0);
            a = p[0]; b = p[1];
        }
        ea_T[k0 + 0][e] = a.x; ea_T[k0 + 1][e] = a.y; ea_T[k0 + 2][e] = a.z; ea_T[k0 + 3][e] = a.w;
        ea_T[k0 + 4][e] = b.x; ea_T[k0 + 5][e] = b.y; ea_T[k0 + 6][e] = b.z; ea_T[k0 + 7][e] = b.w;
    }
    __syncthreads();

    const int w = tid >> 6, l = tid & 63;
    const int t0 = (l & 15) * 4;
    const int e0 = w * 16 + (l >> 4) * 4;

    float z[4][4];
#pragma unroll
    for (int j = 0; j < 4; ++j)
#pragma unroll
        for (int i = 0; i < 4; ++i) z[j][i] = 0.f;

#pragma unroll 8
    for (int k = 0; k < 32; ++k) {
        const float4 ev = *(const float4*)&ea_T[k][e0];
        const float4 wv = *(const float4*)&We_s[k * 64 + t0];
        const float ee[4] = {ev.x, ev.y, ev.z, ev.w};
        const float ww[4] = {wv.x, wv.y, wv.z, wv.w};
#pragma unroll
        for (int j = 0; j < 4; ++j)
#pragma unroll
            for (int i = 0; i < 4; ++i) z[j][i] += ee[j] * ww[i];
    }

    const float4 av = *(const float4*)&att_s[t0];
    const float aa[4] = {av.x, av.y, av.z, av.w};
    float v[4];
#pragma unroll
    for (int j = 0; j < 4; ++j) {
        const int node = ge0 + e0 + j;
        const int nsafe = (node < n) ? node : 0;
        const float4 xlv = *(const float4*)&xl[(size_t)nsafe * 64 + t0];
        const float4 xrv = *(const float4*)&xr[(size_t)nsafe * 64 + t0];
        const float xll[4] = {xlv.x, xlv.y, xlv.z, xlv.w};
        const float xrr[4] = {xrv.x, xrv.y, xrv.z, xrv.w};
        float acc = 0.f;
#pragma unroll
        for (int i = 0; i < 4; ++i) {
            float zz = z[j][i] + xll[i] + xrr[i];
            zz = (zz > 0.f) ? zz : NEG_SLOPE * zz;
            acc += aa[i] * zz;
        }
        v[j] = acc;
    }
#pragma unroll
    for (int m = 1; m < 16; m <<= 1) {
#pragma unroll
        for (int j = 0; j < 4; ++j) v[j] += __shfl_xor(v[j], m);
    }
    if ((l & 15) == 0) {
#pragma unroll
        for (int j = 0; j < 4; ++j) {
            int node = ge0 + e0 + j;
            if (node < n) ex_loop[node] = __expf(v[j]);
        }
    }
}

// ---------- phase B: gather-side aggregation + epilogue ----------
// wave per node; 16 lanes x float4 per xl row, 4 edge slots -> 8 rows in flight.
template <bool FINAL>
__global__ __launch_bounds__(256) void k_node_aggr(
    const float* __restrict__ xl, const int* __restrict__ start,
    const int* __restrict__ src_sorted, const float* __restrict__ ex_sorted,
    const float* __restrict__ ex_loop, const float* __restrict__ bias,
    const float* __restrict__ Wc, const float* __restrict__ bc,
    float* __restrict__ hout, int n) {
    int node = blockIdx.x * 4 + (threadIdx.x >> 6);
    int t = threadIdx.x & 63;
    if (node >= n) return;
    const int es = t >> 4;   // edge slot 0..3
    const int cg = t & 15;   // channel group (float4)
    int a = start[node], b = start[node + 1];

    float4 acc = make_float4(0.f, 0.f, 0.f, 0.f);
    float den = 0.f;
    if (es == 0) {
        float exl = ex_loop[node];
        const float4 xv = *(const float4*)&xl[(size_t)node * 64 + cg * 4];
        acc.x = exl * xv.x; acc.y = exl * xv.y; acc.z = exl * xv.z; acc.w = exl * xv.w;
        den = exl;
    }
    for (int j = a; j < b; j += 64) {
        int m = b - j; if (m > 64) m = 64;
        int sj = 0; float exj = 0.f;
        if (t < m) { sj = src_sorted[j + t]; exj = ex_sorted[j + t]; }
        for (int i = 0; i < m; i += 8) {
            const int i0 = i + es, i1 = i + 4 + es;
            const int s0 = __shfl(sj, i0); const float e0 = __shfl(exj, i0);
            const int s1 = __shfl(sj, i1); const float e1 = __shfl(exj, i1);
            if (i0 < m) {
                const float4 xv = *(const float4*)&xl[(size_t)s0 * 64 + cg * 4];
                acc.x += e0 * xv.x; acc.y += e0 * xv.y;
                acc.z += e0 * xv.z; acc.w += e0 * xv.w;
                den += e0;
            }
            if (i1 < m) {
                const float4 xv = *(const float4*)&xl[(size_t)s1 * 64 + cg * 4];
                acc.x += e1 * xv.x; acc.y += e1 * xv.y;
                acc.z += e1 * xv.z; acc.w += e1 * xv.w;
                den += e1;
            }
        }
    }
#pragma unroll
    for (int mask = 16; mask <= 32; mask <<= 1) {
        acc.x += __shfl_xor(acc.x, mask);
        acc.y += __shfl_xor(acc.y, mask);
        acc.z += __shfl_xor(acc.z, mask);
        acc.w += __shfl_xor(acc.w, mask);
        den   += __shfl_xor(den, mask);
    }
    if (!FINAL) {
        if (es == 0) {
            const float4 bv = *(const float4*)&bias[cg * 4];
            float4 h;
            h.x = fmaxf(acc.x / den + bv.x, 0.f);
            h.y = fmaxf(acc.y / den + bv.y, 0.f);
            h.z = fmaxf(acc.z / den + bv.z, 0.f);
            h.w = fmaxf(acc.w / den + bv.w, 0.f);
            *(float4*)&hout[(size_t)node * 64 + cg * 4] = h;
        }
    } else {
        float v0 = 0.f, v1 = 0.f;
        if (es == 0) {
            const float4 bv = *(const float4*)&bias[cg * 4];
            const float h0 = fmaxf(acc.x / den + bv.x, 0.f);
            const float h1 = fmaxf(acc.y / den + bv.y, 0.f);
            const float h2 = fmaxf(acc.z / den + bv.z, 0.f);
            const float h3 = fmaxf(acc.w / den + bv.w, 0.f);
            const int c0 = cg * 4;
            v0 = h0 * Wc[(c0 + 0) * 2 + 0] + h1 * Wc[(c0 + 1) * 2 + 0]
               + h2 * Wc[(c0 + 2) * 2 + 0] + h3 * Wc[(c0 + 3) * 2 + 0];
            v1 = h0 * Wc[(c0 + 0) * 2 + 1] + h1 * Wc[(c0 + 1) * 2 + 1]
               + h2 * Wc[(c0 + 2) * 2 + 1] + h3 * Wc[(c0 + 3) * 2 + 1];
        }
#pragma unroll
        for (int mask = 1; mask <= 8; mask <<= 1) {
            v0 += __shfl_xor(v0, mask);
            v1 += __shfl_xor(v1, mask);
        }
        if (t == 0) {
            hout[(size_t)node * 2 + 0] = v0 + bc[0];
            hout[(size_t)node * 2 + 1] = v1 + bc[1];
        }
    }
}

extern "C" void kernel_launch(void* const* d_in, const int* in_sizes, int n_in,
                              void* d_out, int out_size, void* d_ws, size_t ws_size,
                              hipStream_t stream) {
    const float* x     = (const float*)d_in[0];
    const int*   ei    = (const int*)d_in[1];
    const float* eattr = (const float*)d_in[2];
    const float* Wl1 = (const float*)d_in[3];
    const float* bl1 = (const float*)d_in[4];
    const float* Wr1 = (const float*)d_in[5];
    const float* br1 = (const float*)d_in[6];
    const float* We1 = (const float*)d_in[7];
    const float* att1 = (const float*)d_in[8];
    const float* bias1 = (const float*)d_in[9];
    const float* Wl2 = (const float*)d_in[10];
    const float* bl2 = (const float*)d_in[11];
    const float* Wr2 = (const float*)d_in[12];
    const float* br2 = (const float*)d_in[13];
    const float* We2 = (const float*)d_in[14];
    const float* att2 = (const float*)d_in[15];
    const float* bias2 = (const float*)d_in[16];
    const float* Wc = (const float*)d_in[17];
    const float* bc = (const float*)d_in[18];

    const int N = in_sizes[0] / 128;
    const int E = in_sizes[1] / 2;
    const int* src = ei;
    const int* dst = ei + E;

    char* w = (char*)d_ws;
    auto alloc = [&](size_t bytes) {
        char* p = w;
        w += (bytes + 255) & ~(size_t)255;
        return p;
    };
    float* xl         = (float*)alloc((size_t)N * 64 * 4);
    float* xr         = (float*)alloc((size_t)N * 64 * 4);
    float* hbuf       = (float*)alloc((size_t)N * 64 * 4);
    float* loop_sum   = (float*)alloc((size_t)N * 32 * 4);
    float* loop_attr  = (float*)alloc((size_t)N * 32 * 4);
    float* ex_loop    = (float*)alloc((size_t)N * 4);
    int*   deg_i      = (int*)alloc((size_t)N * 4);
    int*   start      = (int*)alloc((size_t)(N + 1) * 4);
    int*   cursor     = (int*)alloc((size_t)N * 4);
    int*   perm       = (int*)alloc((size_t)E * 4);
    int*   src_sorted = (int*)alloc((size_t)E * 4);
    int*   dst_sorted = (int*)alloc((size_t)E * 4);
    float* ex_sorted  = (float*)alloc((size_t)E * 4);

    const int THREADS = 256;
    const int score_blocks = (E + 63) / 64;
    const int loop_blocks = (N + 63) / 64;
    const int node4_blocks = (N + 3) / 4;
    const int edge_blocks = (E + THREADS - 1) / THREADS;

    // ---- CSR by dst (shared by both layers) ----
    hipMemsetAsync(deg_i, 0, (size_t)N * 4, stream);
    hipMemsetAsync(cursor, 0, (size_t)N * 4, stream);
    k_hist<<<edge_blocks, THREADS, 0, stream>>>(dst, E, deg_i);
    k_scan<<<1, 1024, 0, stream>>>(deg_i, start, N);
    k_fill<<<edge_blocks, THREADS, 0, stream>>>(src, dst, E, start, cursor,
                                                perm, src_sorted, dst_sorted);

    // ---- layer 1 (score pass also accumulates loop_sum) ----
    k_node_transform<128><<<node4_blocks, THREADS, 0, stream>>>(x, Wl1, bl1, Wr1, br1, xl, xr, N);
    hipMemsetAsync(loop_sum, 0, (size_t)N * 32 * 4, stream);
    k_edge_score<true><<<score_blocks, THREADS, 0, stream>>>(
        xl, xr, eattr, We1, att1, perm, src_sorted, dst_sorted, E, ex_sorted, loop_sum);
    {
        int blocks = (N * 32 + THREADS - 1) / THREADS;
        k_loop_norm<<<blocks, THREADS, 0, stream>>>(loop_sum, deg_i, loop_attr, N);
    }
    k_loop_score<<<loop_blocks, THREADS, 0, stream>>>(xl, xr, loop_attr, We1, att1, N, ex_loop);
    k_node_aggr<false><<<node4_blocks, THREADS, 0, stream>>>(xl, start, src_sorted, ex_sorted,
                                                             ex_loop, bias1, Wc, bc, hbuf, N);

    // ---- layer 2 ----
    k_node_transform<64><<<node4_blocks, THREADS, 0, stream>>>(hbuf, Wl2, bl2, Wr2, br2, xl, xr, N);
    k_loop_score<<<loop_blocks, THREADS, 0, stream>>>(xl, xr, loop_attr, We2, att2, N, ex_loop);
    k_edge_score<false><<<score_blocks, THREADS, 0, stream>>>(
        xl, xr, eattr, We2, att2, perm, src_sorted, dst_sorted, E, ex_sorted, loop_sum);
    k_node_aggr<true><<<node4_blocks, THREADS, 0, stream>>>(xl, start, src_sorted, ex_sorted,
                                                            ex_loop, bias2, Wc, bc, (float*)d_out, N);
}

// Round 8
// 876.563 us; speedup vs baseline: 2.0604x; 1.0600x over previous
//
#include <hip/hip_runtime.h>
#include <hip/hip_bf16.h>

#define NEG_SLOPE 0.2f

// packed fp32 FMA, broadcasting LO or HI half of b across both lanes (VOP3P op_sel)
__device__ __forceinline__ float2 pk_fma_lo(float2 a, float2 b, float2 c) {
    float2 d;
    asm("v_pk_fma_f32 %0, %1, %2, %3 op_sel:[0,0,0] op_sel_hi:[1,0,1]"
        : "=v"(d) : "v"(a), "v"(b), "v"(c));
    return d;
}
__device__ __forceinline__ float2 pk_fma_hi(float2 a, float2 b, float2 c) {
    float2 d;
    asm("v_pk_fma_f32 %0, %1, %2, %3 op_sel:[0,1,0] op_sel_hi:[1,1,1]"
        : "=v"(d) : "v"(a), "v"(b), "v"(c));
    return d;
}

// ---------- CSR build ----------
__global__ void k_hist(const int* __restrict__ dst, int E, int* __restrict__ deg) {
    int e = blockIdx.x * 256 + threadIdx.x;
    if (e < E) atomicAdd(&deg[dst[e]], 1);
}

__global__ __launch_bounds__(1024) void k_scan(const int* __restrict__ deg,
                                               int* __restrict__ start, int n) {
    __shared__ int wsum[16];
    __shared__ int carry_s;
    if (threadIdx.x == 0) carry_s = 0;
    __syncthreads();
    const int lane = threadIdx.x & 63;
    const int w = threadIdx.x >> 6;
    for (int base = 0; base < n; base += 1024) {
        int i = base + (int)threadIdx.x;
        int v = (i < n) ? deg[i] : 0;
        int s = v;
#pragma unroll
        for (int o = 1; o < 64; o <<= 1) {
            int u = __shfl_up(s, o);
            if (lane >= o) s += u;
        }
        if (lane == 63) wsum[w] = s;
        __syncthreads();
        if (w == 0) {
            int ws = (lane < 16) ? wsum[lane] : 0;
#pragma unroll
            for (int o = 1; o < 16; o <<= 1) {
                int u = __shfl_up(ws, o);
                if (lane >= o) ws += u;
            }
            if (lane < 16) wsum[lane] = ws;
        }
        __syncthreads();
        int carry = carry_s;
        int woff = (w == 0) ? 0 : wsum[w - 1];
        int incl = s + woff + carry;
        if (i < n) start[i] = incl - v;
        __syncthreads();
        if (threadIdx.x == 1023) carry_s = incl;
        __syncthreads();
    }
    if (threadIdx.x == 0) start[n] = carry_s;
}

__global__ void k_fill(const int* __restrict__ src, const int* __restrict__ dst, int E,
                       const int* __restrict__ start, int* __restrict__ cursor,
                       int* __restrict__ perm, int* __restrict__ src_sorted,
                       int* __restrict__ dst_sorted) {
    int e = blockIdx.x * 256 + threadIdx.x;
    if (e >= E) return;
    int d = dst[e];
    int idx = start[d] + atomicAdd(&cursor[d], 1);
    perm[idx] = e;
    src_sorted[idx] = src[e];
    dst_sorted[idx] = d;
}

// ---------- self-loop attr: gather-side segment mean ----------
// 8-lane group per edge row (float4): 8 rows in flight per wave.
__global__ __launch_bounds__(256) void k_loop_csr(
    const float* __restrict__ eattr, const int* __restrict__ perm,
    const int* __restrict__ start, float* __restrict__ loop_attr, int n) {
    int node = blockIdx.x * 4 + (threadIdx.x >> 6);
    int t = threadIdx.x & 63;
    if (node >= n) return;
    int a = start[node], b = start[node + 1];
    int g = t >> 3, gl = t & 7;
    float4 acc = make_float4(0.f, 0.f, 0.f, 0.f);
    for (int j = a + g; j < b; j += 8) {
        int e = perm[j];
        const float4 v = *(const float4*)&eattr[(size_t)e * 32 + gl * 4];
        acc.x += v.x; acc.y += v.y; acc.z += v.z; acc.w += v.w;
    }
#pragma unroll
    for (int mask = 8; mask <= 32; mask <<= 1) {
        acc.x += __shfl_xor(acc.x, mask);
        acc.y += __shfl_xor(acc.y, mask);
        acc.z += __shfl_xor(acc.z, mask);
        acc.w += __shfl_xor(acc.w, mask);
    }
    if (t < 8) {
        float deg = fmaxf((float)(b - a), 1.f);
        float4 o = make_float4(acc.x / deg, acc.y / deg, acc.z / deg, acc.w / deg);
        *(float4*)&loop_attr[(size_t)node * 32 + gl * 4] = o;
    }
}

// ---------- node transform: xl = h@Wl+bl, xr = h@Wr+br ----------
template <int DIN>
__global__ void k_node_transform(const float* __restrict__ h,
                                 const float* __restrict__ Wl, const float* __restrict__ bl,
                                 const float* __restrict__ Wr, const float* __restrict__ br,
                                 float* __restrict__ xl, float* __restrict__ xr, int n) {
    __shared__ float hs[4][DIN];
    int node0 = blockIdx.x * 4;
    int tid = threadIdx.x;
    for (int idx = tid; idx < 4 * DIN; idx += 256) {
        int ln = idx / DIN, k = idx % DIN;
        int node = node0 + ln;
        hs[ln][k] = (node < n) ? h[(long long)node * DIN + k] : 0.f;
    }
    __syncthreads();
    int ln = tid >> 6;
    int j = tid & 63;
    int node = node0 + ln;
    if (node >= n) return;
    float al = bl[j], ar = br[j];
#pragma unroll 8
    for (int k = 0; k < DIN; ++k) {
        float hv = hs[ln][k];
        al += hv * Wl[k * 64 + j];
        ar += hv * Wr[k * 64 + j];
    }
    xl[(long long)node * 64 + j] = al;
    xr[(long long)node * 64 + j] = ar;
}

// ---------- phase A: edge scores over dst-SORTED edges -> ex_sorted ----------
// 64 sorted edges/block. perm prefetched FIRST (overlaps We/att staging);
// pk_fma GEMM tile; xr[dst] L1-cached via sortedness; coalesced ex write;
// NO in-kernel loop_sum (that caused R7's 4-way ea_T bank conflicts).
__global__ __launch_bounds__(256) void k_edge_score(
    const float* __restrict__ xl, const float* __restrict__ xr,
    const float* __restrict__ eattr,
    const float* __restrict__ We, const float* __restrict__ att,
    const int* __restrict__ perm, const int* __restrict__ src_sorted,
    const int* __restrict__ dst_sorted, int E,
    float* __restrict__ ex_sorted) {
    __shared__ float We_s[32 * 64];
    __shared__ float ea_T[32][68];
    __shared__ float att_s[64];
    __shared__ int s_s[64], d_s[64];

    const int tid = threadIdx.x;
    const int ge0 = blockIdx.x * 64;

    // issue the dependent perm load FIRST so eattr gather overlaps staging
    const int e_st = tid & 63;
    const int k0 = (tid >> 6) * 8;
    const int ge_st = ge0 + e_st;
    const int pe = (ge_st < E) ? perm[ge_st] : -1;

    for (int i = tid; i < 2048; i += 256) We_s[i] = We[i];
    if (tid < 64) att_s[tid] = att[tid];
    if (tid >= 64 && tid < 128) {
        int eb = tid - 64, ge = ge0 + eb;
        s_s[eb] = (ge < E) ? src_sorted[ge] : 0;
    }
    if (tid >= 128 && tid < 192) {
        int eb = tid - 128, ge = ge0 + eb;
        d_s[eb] = (ge < E) ? dst_sorted[ge] : 0;
    }
    {
        float4 a = make_float4(0.f, 0.f, 0.f, 0.f), b = a;
        if (pe >= 0) {
            const float4* p = (const float4*)(eattr + (size_t)pe * 32 + k0);
            a = p[0]; b = p[1];
        }
        ea_T[k0 + 0][e_st] = a.x; ea_T[k0 + 1][e_st] = a.y;
        ea_T[k0 + 2][e_st] = a.z; ea_T[k0 + 3][e_st] = a.w;
        ea_T[k0 + 4][e_st] = b.x; ea_T[k0 + 5][e_st] = b.y;
        ea_T[k0 + 6][e_st] = b.z; ea_T[k0 + 7][e_st] = b.w;
    }
    __syncthreads();

    const int w = tid >> 6, l = tid & 63;
    const int t0 = (l & 15) * 4;            // channel group
    const int e0 = w * 16 + (l >> 4) * 4;   // edge group (4 sorted edges)

    // zp[edge-pair][channel]: .x = even edge, .y = odd edge
    float2 zp[2][4];
#pragma unroll
    for (int p = 0; p < 2; ++p)
#pragma unroll
        for (int i = 0; i < 4; ++i) zp[p][i] = make_float2(0.f, 0.f);

#pragma unroll 8
    for (int k = 0; k < 32; ++k) {
        const float4 ev = *(const float4*)&ea_T[k][e0];
        const float4 wv = *(const float4*)&We_s[k * 64 + t0];
        const float2 ep0 = make_float2(ev.x, ev.y);
        const float2 ep1 = make_float2(ev.z, ev.w);
        const float2 wp0 = make_float2(wv.x, wv.y);
        const float2 wp1 = make_float2(wv.z, wv.w);
        zp[0][0] = pk_fma_lo(ep0, wp0, zp[0][0]);
        zp[0][1] = pk_fma_hi(ep0, wp0, zp[0][1]);
        zp[0][2] = pk_fma_lo(ep0, wp1, zp[0][2]);
        zp[0][3] = pk_fma_hi(ep0, wp1, zp[0][3]);
        zp[1][0] = pk_fma_lo(ep1, wp0, zp[1][0]);
        zp[1][1] = pk_fma_hi(ep1, wp0, zp[1][1]);
        zp[1][2] = pk_fma_lo(ep1, wp1, zp[1][2]);
        zp[1][3] = pk_fma_hi(ep1, wp1, zp[1][3]);
    }

    const float4 av = *(const float4*)&att_s[t0];
    const float aa[4] = {av.x, av.y, av.z, av.w};
    float v[4];
#pragma unroll
    for (int j = 0; j < 4; ++j) {
        const int eb = e0 + j;
        const int s = s_s[eb];
        const int d = d_s[eb];
        const float4 xlv = *(const float4*)&xl[(size_t)s * 64 + t0];
        const float4 xrv = *(const float4*)&xr[(size_t)d * 64 + t0];
        const float xll[4] = {xlv.x, xlv.y, xlv.z, xlv.w};
        const float xrr[4] = {xrv.x, xrv.y, xrv.z, xrv.w};
        const int p = j >> 1;
        float zj[4];
        if (j & 1) { zj[0] = zp[p][0].y; zj[1] = zp[p][1].y; zj[2] = zp[p][2].y; zj[3] = zp[p][3].y; }
        else       { zj[0] = zp[p][0].x; zj[1] = zp[p][1].x; zj[2] = zp[p][2].x; zj[3] = zp[p][3].x; }
        float acc = 0.f;
#pragma unroll
        for (int i = 0; i < 4; ++i) {
            float zz = zj[i] + xll[i] + xrr[i];
            zz = (zz > 0.f) ? zz : NEG_SLOPE * zz;
            acc += aa[i] * zz;
        }
        v[j] = acc;
    }
#pragma unroll
    for (int m = 1; m < 16; m <<= 1) {
#pragma unroll
        for (int j = 0; j < 4; ++j) v[j] += __shfl_xor(v[j], m);
    }
    if ((l & 15) == 0) {
#pragma unroll
        for (int j = 0; j < 4; ++j) {
            int ge = ge0 + e0 + j;
            if (ge < E) ex_sorted[ge] = __expf(v[j]);
        }
    }
}

// ---------- self-loop scores ----------
__global__ __launch_bounds__(256) void k_loop_score(
    const float* __restrict__ xl, const float* __restrict__ xr,
    const float* __restrict__ loop_attr,
    const float* __restrict__ We, const float* __restrict__ att,
    int n, float* __restrict__ ex_loop) {
    __shared__ float We_s[32 * 64];
    __shared__ float ea_T[32][68];
    __shared__ float att_s[64];

    const int tid = threadIdx.x;
    const int ge0 = blockIdx.x * 64;

    for (int i = tid; i < 2048; i += 256) We_s[i] = We[i];
    if (tid < 64) att_s[tid] = att[tid];
    {
        int e = tid & 63;
        int k0 = (tid >> 6) * 8;
        int ge = ge0 + e;
        float4 a = make_float4(0.f, 0.f, 0.f, 0.f), b = a;
        if (ge < n) {
            const float4* p = (const float4*)(loop_attr + (size_t)ge * 32 + k0);
            a = p[0]; b = p[1];
        }
        ea_T[k0 + 0][e] = a.x; ea_T[k0 + 1][e] = a.y; ea_T[k0 + 2][e] = a.z; ea_T[k0 + 3][e] = a.w;
        ea_T[k0 + 4][e] = b.x; ea_T[k0 + 5][e] = b.y; ea_T[k0 + 6][e] = b.z; ea_T[k0 + 7][e] = b.w;
    }
    __syncthreads();

    const int w = tid >> 6, l = tid & 63;
    const int t0 = (l & 15) * 4;
    const int e0 = w * 16 + (l >> 4) * 4;

    float z[4][4];
#pragma unroll
    for (int j = 0; j < 4; ++j)
#pragma unroll
        for (int i = 0; i < 4; ++i) z[j][i] = 0.f;

#pragma unroll 8
    for (int k = 0; k < 32; ++k) {
        const float4 ev = *(const float4*)&ea_T[k][e0];
        const float4 wv = *(const float4*)&We_s[k * 64 + t0];
        const float ee[4] = {ev.x, ev.y, ev.z, ev.w};
        const float ww[4] = {wv.x, wv.y, wv.z, wv.w};
#pragma unroll
        for (int j = 0; j < 4; ++j)
#pragma unroll
            for (int i = 0; i < 4; ++i) z[j][i] += ee[j] * ww[i];
    }

    const float4 av = *(const float4*)&att_s[t0];
    const float aa[4] = {av.x, av.y, av.z, av.w};
    float v[4];
#pragma unroll
    for (int j = 0; j < 4; ++j) {
        const int node = ge0 + e0 + j;
        const int nsafe = (node < n) ? node : 0;
        const float4 xlv = *(const float4*)&xl[(size_t)nsafe * 64 + t0];
        const float4 xrv = *(const float4*)&xr[(size_t)nsafe * 64 + t0];
        const float xll[4] = {xlv.x, xlv.y, xlv.z, xlv.w};
        const float xrr[4] = {xrv.x, xrv.y, xrv.z, xrv.w};
        float acc = 0.f;
#pragma unroll
        for (int i = 0; i < 4; ++i) {
            float zz = z[j][i] + xll[i] + xrr[i];
            zz = (zz > 0.f) ? zz : NEG_SLOPE * zz;
            acc += aa[i] * zz;
        }
        v[j] = acc;
    }
#pragma unroll
    for (int m = 1; m < 16; m <<= 1) {
#pragma unroll
        for (int j = 0; j < 4; ++j) v[j] += __shfl_xor(v[j], m);
    }
    if ((l & 15) == 0) {
#pragma unroll
        for (int j = 0; j < 4; ++j) {
            int node = ge0 + e0 + j;
            if (node < n) ex_loop[node] = __expf(v[j]);
        }
    }
}

// ---------- phase B: gather-side aggregation + epilogue ----------
// wave per node; 16 lanes x float4 per xl row, 4 edge slots -> 8 rows in flight.
template <bool FINAL>
__global__ __launch_bounds__(256) void k_node_aggr(
    const float* __restrict__ xl, const int* __restrict__ start,
    const int* __restrict__ src_sorted, const float* __restrict__ ex_sorted,
    const float* __restrict__ ex_loop, const float* __restrict__ bias,
    const float* __restrict__ Wc, const float* __restrict__ bc,
    float* __restrict__ hout, int n) {
    int node = blockIdx.x * 4 + (threadIdx.x >> 6);
    int t = threadIdx.x & 63;
    if (node >= n) return;
    const int es = t >> 4;   // edge slot 0..3
    const int cg = t & 15;   // channel group (float4)
    int a = start[node], b = start[node + 1];

    float4 acc = make_float4(0.f, 0.f, 0.f, 0.f);
    float den = 0.f;
    if (es == 0) {
        float exl = ex_loop[node];
        const float4 xv = *(const float4*)&xl[(size_t)node * 64 + cg * 4];
        acc.x = exl * xv.x; acc.y = exl * xv.y; acc.z = exl * xv.z; acc.w = exl * xv.w;
        den = exl;
    }
    for (int j = a; j < b; j += 64) {
        int m = b - j; if (m > 64) m = 64;
        int sj = 0; float exj = 0.f;
        if (t < m) { sj = src_sorted[j + t]; exj = ex_sorted[j + t]; }
        for (int i = 0; i < m; i += 8) {
            const int i0 = i + es, i1 = i + 4 + es;
            const int s0 = __shfl(sj, i0); const float e0 = __shfl(exj, i0);
            const int s1 = __shfl(sj, i1); const float e1 = __shfl(exj, i1);
            if (i0 < m) {
                const float4 xv = *(const float4*)&xl[(size_t)s0 * 64 + cg * 4];
                acc.x += e0 * xv.x; acc.y += e0 * xv.y;
                acc.z += e0 * xv.z; acc.w += e0 * xv.w;
                den += e0;
            }
            if (i1 < m) {
                const float4 xv = *(const float4*)&xl[(size_t)s1 * 64 + cg * 4];
                acc.x += e1 * xv.x; acc.y += e1 * xv.y;
                acc.z += e1 * xv.z; acc.w += e1 * xv.w;
                den += e1;
            }
        }
    }
#pragma unroll
    for (int mask = 16; mask <= 32; mask <<= 1) {
        acc.x += __shfl_xor(acc.x, mask);
        acc.y += __shfl_xor(acc.y, mask);
        acc.z += __shfl_xor(acc.z, mask);
        acc.w += __shfl_xor(acc.w, mask);
        den   += __shfl_xor(den, mask);
    }
    if (!FINAL) {
        if (es == 0) {
            const float4 bv = *(const float4*)&bias[cg * 4];
            float4 h;
            h.x = fmaxf(acc.x / den + bv.x, 0.f);
            h.y = fmaxf(acc.y / den + bv.y, 0.f);
            h.z = fmaxf(acc.z / den + bv.z, 0.f);
            h.w = fmaxf(acc.w / den + bv.w, 0.f);
            *(float4*)&hout[(size_t)node * 64 + cg * 4] = h;
        }
    } else {
        float v0 = 0.f, v1 = 0.f;
        if (es == 0) {
            const float4 bv = *(const float4*)&bias[cg * 4];
            const float h0 = fmaxf(acc.x / den + bv.x, 0.f);
            const float h1 = fmaxf(acc.y / den + bv.y, 0.f);
            const float h2 = fmaxf(acc.z / den + bv.z, 0.f);
            const float h3 = fmaxf(acc.w / den + bv.w, 0.f);
            const int c0 = cg * 4;
            v0 = h0 * Wc[(c0 + 0) * 2 + 0] + h1 * Wc[(c0 + 1) * 2 + 0]
               + h2 * Wc[(c0 + 2) * 2 + 0] + h3 * Wc[(c0 + 3) * 2 + 0];
            v1 = h0 * Wc[(c0 + 0) * 2 + 1] + h1 * Wc[(c0 + 1) * 2 + 1]
               + h2 * Wc[(c0 + 2) * 2 + 1] + h3 * Wc[(c0 + 3) * 2 + 1];
        }
#pragma unroll
        for (int mask = 1; mask <= 8; mask <<= 1) {
            v0 += __shfl_xor(v0, mask);
            v1 += __shfl_xor(v1, mask);
        }
        if (t == 0) {
            hout[(size_t)node * 2 + 0] = v0 + bc[0];
            hout[(size_t)node * 2 + 1] = v1 + bc[1];
        }
    }
}

extern "C" void kernel_launch(void* const* d_in, const int* in_sizes, int n_in,
                              void* d_out, int out_size, void* d_ws, size_t ws_size,
                              hipStream_t stream) {
    const float* x     = (const float*)d_in[0];
    const int*   ei    = (const int*)d_in[1];
    const float* eattr = (const float*)d_in[2];
    const float* Wl1 = (const float*)d_in[3];
    const float* bl1 = (const float*)d_in[4];
    const float* Wr1 = (const float*)d_in[5];
    const float* br1 = (const float*)d_in[6];
    const float* We1 = (const float*)d_in[7];
    const float* att1 = (const float*)d_in[8];
    const float* bias1 = (const float*)d_in[9];
    const float* Wl2 = (const float*)d_in[10];
    const float* bl2 = (const float*)d_in[11];
    const float* Wr2 = (const float*)d_in[12];
    const float* br2 = (const float*)d_in[13];
    const float* We2 = (const float*)d_in[14];
    const float* att2 = (const float*)d_in[15];
    const float* bias2 = (const float*)d_in[16];
    const float* Wc = (const float*)d_in[17];
    const float* bc = (const float*)d_in[18];

    const int N = in_sizes[0] / 128;
    const int E = in_sizes[1] / 2;
    const int* src = ei;
    const int* dst = ei + E;

    char* w = (char*)d_ws;
    auto alloc = [&](size_t bytes) {
        char* p = w;
        w += (bytes + 255) & ~(size_t)255;
        return p;
    };
    float* xl         = (float*)alloc((size_t)N * 64 * 4);
    float* xr         = (float*)alloc((size_t)N * 64 * 4);
    float* hbuf       = (float*)alloc((size_t)N * 64 * 4);
    float* loop_attr  = (float*)alloc((size_t)N * 32 * 4);
    float* ex_loop    = (float*)alloc((size_t)N * 4);
    int*   deg_i      = (int*)alloc((size_t)N * 4);
    int*   start      = (int*)alloc((size_t)(N + 1) * 4);
    int*   cursor     = (int*)alloc((size_t)N * 4);
    int*   perm       = (int*)alloc((size_t)E * 4);
    int*   src_sorted = (int*)alloc((size_t)E * 4);
    int*   dst_sorted = (int*)alloc((size_t)E * 4);
    float* ex_sorted  = (float*)alloc((size_t)E * 4);

    const int THREADS = 256;
    const int score_blocks = (E + 63) / 64;
    const int loop_blocks = (N + 63) / 64;
    const int node4_blocks = (N + 3) / 4;
    const int edge_blocks = (E + THREADS - 1) / THREADS;

    // ---- CSR by dst (shared by both layers) ----
    hipMemsetAsync(deg_i, 0, (size_t)N * 4, stream);
    hipMemsetAsync(cursor, 0, (size_t)N * 4, stream);
    k_hist<<<edge_blocks, THREADS, 0, stream>>>(dst, E, deg_i);
    k_scan<<<1, 1024, 0, stream>>>(deg_i, start, N);
    k_fill<<<edge_blocks, THREADS, 0, stream>>>(src, dst, E, start, cursor,
                                                perm, src_sorted, dst_sorted);
    k_loop_csr<<<node4_blocks, THREADS, 0, stream>>>(eattr, perm, start, loop_attr, N);

    // ---- layer 1 ----
    k_node_transform<128><<<node4_blocks, THREADS, 0, stream>>>(x, Wl1, bl1, Wr1, br1, xl, xr, N);
    k_edge_score<<<score_blocks, THREADS, 0, stream>>>(
        xl, xr, eattr, We1, att1, perm, src_sorted, dst_sorted, E, ex_sorted);
    k_loop_score<<<loop_blocks, THREADS, 0, stream>>>(xl, xr, loop_attr, We1, att1, N, ex_loop);
    k_node_aggr<false><<<node4_blocks, THREADS, 0, stream>>>(xl, start, src_sorted, ex_sorted,
                                                             ex_loop, bias1, Wc, bc, hbuf, N);

    // ---- layer 2 ----
    k_node_transform<64><<<node4_blocks, THREADS, 0, stream>>>(hbuf, Wl2, bl2, Wr2, br2, xl, xr, N);
    k_loop_score<<<loop_blocks, THREADS, 0, stream>>>(xl, xr, loop_attr, We2, att2, N, ex_loop);
    k_edge_score<<<score_blocks, THREADS, 0, stream>>>(
        xl, xr, eattr, We2, att2, perm, src_sorted, dst_sorted, E, ex_sorted);
    k_node_aggr<true><<<node4_blocks, THREADS, 0, stream>>>(xl, start, src_sorted, ex_sorted,
                                                            ex_loop, bias2, Wc, bc, (float*)d_out, N);
}

// Round 9
// 876.380 us; speedup vs baseline: 2.0609x; 1.0002x over previous
//
#include <hip/hip_runtime.h>
#include <hip/hip_bf16.h>

#define NEG_SLOPE 0.2f

// ---------- CSR build ----------
__global__ void k_hist(const int* __restrict__ dst, int E, int* __restrict__ deg) {
    int e = blockIdx.x * 256 + threadIdx.x;
    if (e < E) atomicAdd(&deg[dst[e]], 1);
}

__global__ __launch_bounds__(1024) void k_scan(const int* __restrict__ deg,
                                               int* __restrict__ start, int n) {
    __shared__ int wsum[16];
    __shared__ int carry_s;
    if (threadIdx.x == 0) carry_s = 0;
    __syncthreads();
    const int lane = threadIdx.x & 63;
    const int w = threadIdx.x >> 6;
    for (int base = 0; base < n; base += 1024) {
        int i = base + (int)threadIdx.x;
        int v = (i < n) ? deg[i] : 0;
        int s = v;
#pragma unroll
        for (int o = 1; o < 64; o <<= 1) {
            int u = __shfl_up(s, o);
            if (lane >= o) s += u;
        }
        if (lane == 63) wsum[w] = s;
        __syncthreads();
        if (w == 0) {
            int ws = (lane < 16) ? wsum[lane] : 0;
#pragma unroll
            for (int o = 1; o < 16; o <<= 1) {
                int u = __shfl_up(ws, o);
                if (lane >= o) ws += u;
            }
            if (lane < 16) wsum[lane] = ws;
        }
        __syncthreads();
        int carry = carry_s;
        int woff = (w == 0) ? 0 : wsum[w - 1];
        int incl = s + woff + carry;
        if (i < n) start[i] = incl - v;
        __syncthreads();
        if (threadIdx.x == 1023) carry_s = incl;
        __syncthreads();
    }
    if (threadIdx.x == 0) start[n] = carry_s;
}

__global__ void k_fill(const int* __restrict__ src, const int* __restrict__ dst, int E,
                       const int* __restrict__ start, int* __restrict__ cursor,
                       int* __restrict__ perm, int* __restrict__ src_sorted,
                       int* __restrict__ sortpos) {
    int e = blockIdx.x * 256 + threadIdx.x;
    if (e >= E) return;
    int d = dst[e];
    int idx = start[d] + atomicAdd(&cursor[d], 1);
    perm[idx] = e;
    src_sorted[idx] = src[e];
    sortpos[e] = idx;
}

// ---------- self-loop attr: gather-side segment mean ----------
// 8-lane group per edge row (float4): 8 rows in flight per wave.
__global__ __launch_bounds__(256) void k_loop_csr(
    const float* __restrict__ eattr, const int* __restrict__ perm,
    const int* __restrict__ start, float* __restrict__ loop_attr, int n) {
    int node = blockIdx.x * 4 + (threadIdx.x >> 6);
    int t = threadIdx.x & 63;
    if (node >= n) return;
    int a = start[node], b = start[node + 1];
    int g = t >> 3, gl = t & 7;
    float4 acc = make_float4(0.f, 0.f, 0.f, 0.f);
    for (int j = a + g; j < b; j += 8) {
        int e = perm[j];
        const float4 v = *(const float4*)&eattr[(size_t)e * 32 + gl * 4];
        acc.x += v.x; acc.y += v.y; acc.z += v.z; acc.w += v.w;
    }
#pragma unroll
    for (int mask = 8; mask <= 32; mask <<= 1) {
        acc.x += __shfl_xor(acc.x, mask);
        acc.y += __shfl_xor(acc.y, mask);
        acc.z += __shfl_xor(acc.z, mask);
        acc.w += __shfl_xor(acc.w, mask);
    }
    if (t < 8) {
        float deg = fmaxf((float)(b - a), 1.f);
        float4 o = make_float4(acc.x / deg, acc.y / deg, acc.z / deg, acc.w / deg);
        *(float4*)&loop_attr[(size_t)node * 32 + gl * 4] = o;
    }
}

// ---------- node transform: xl = h@Wl+bl, xr = h@Wr+br ----------
template <int DIN>
__global__ void k_node_transform(const float* __restrict__ h,
                                 const float* __restrict__ Wl, const float* __restrict__ bl,
                                 const float* __restrict__ Wr, const float* __restrict__ br,
                                 float* __restrict__ xl, float* __restrict__ xr, int n) {
    __shared__ float hs[4][DIN];
    int node0 = blockIdx.x * 4;
    int tid = threadIdx.x;
    for (int idx = tid; idx < 4 * DIN; idx += 256) {
        int ln = idx / DIN, k = idx % DIN;
        int node = node0 + ln;
        hs[ln][k] = (node < n) ? h[(long long)node * DIN + k] : 0.f;
    }
    __syncthreads();
    int ln = tid >> 6;
    int j = tid & 63;
    int node = node0 + ln;
    if (node >= n) return;
    float al = bl[j], ar = br[j];
#pragma unroll 8
    for (int k = 0; k < DIN; ++k) {
        float hv = hs[ln][k];
        al += hv * Wl[k * 64 + j];
        ar += hv * Wr[k * 64 + j];
    }
    xl[(long long)node * 64 + j] = al;
    xr[(long long)node * 64 + j] = ar;
}

// ---------- phase A: edge scores, STREAMING original order ----------
// 128 edges/block (We staging amortized 2x vs 64). Scalar FMA GEMM tile
// (pk_fma asm caused bank-conflict codegen in R7/R8). ex scattered via
// sortpos (4B writes, cheap). Each lane-slot handles 8 edges x 4 channels.
__global__ __launch_bounds__(256) void k_edge_score(
    const float* __restrict__ xl, const float* __restrict__ xr,
    const float* __restrict__ eattr,
    const float* __restrict__ We, const float* __restrict__ att,
    const int* __restrict__ src, const int* __restrict__ dst,
    const int* __restrict__ sortpos, int E,
    float* __restrict__ ex_sorted) {
    __shared__ __align__(16) float We_s[32 * 64];
    __shared__ __align__(16) float ea_T[32][132];
    __shared__ float att_s[64];
    __shared__ int s_s[128], d_s[128], sp_s[128];

    const int tid = threadIdx.x;
    const int ge0 = blockIdx.x * 128;

    // edge metadata (coalesced, original order)
    if (tid < 128) {
        int ge = ge0 + tid;
        bool ok = ge < E;
        s_s[tid] = ok ? src[ge] : 0;
        d_s[tid] = ok ? dst[ge] : 0;
        sp_s[tid] = ok ? sortpos[ge] : 0;
    }
    // eattr: 2 threads per row, 16 floats each (streaming rows)
    {
        const int e = tid & 127;
        const int kc = (tid >> 7) * 16;
        const int ge = ge0 + e;
        float4 a = make_float4(0.f, 0.f, 0.f, 0.f), b = a, c = a, d4 = a;
        if (ge < E) {
            const float4* p = (const float4*)(eattr + (size_t)ge * 32 + kc);
            a = p[0]; b = p[1]; c = p[2]; d4 = p[3];
        }
        ea_T[kc + 0][e] = a.x;  ea_T[kc + 1][e] = a.y;  ea_T[kc + 2][e] = a.z;  ea_T[kc + 3][e] = a.w;
        ea_T[kc + 4][e] = b.x;  ea_T[kc + 5][e] = b.y;  ea_T[kc + 6][e] = b.z;  ea_T[kc + 7][e] = b.w;
        ea_T[kc + 8][e] = c.x;  ea_T[kc + 9][e] = c.y;  ea_T[kc + 10][e] = c.z; ea_T[kc + 11][e] = c.w;
        ea_T[kc + 12][e] = d4.x; ea_T[kc + 13][e] = d4.y; ea_T[kc + 14][e] = d4.z; ea_T[kc + 15][e] = d4.w;
    }
    for (int i = tid; i < 2048; i += 256) We_s[i] = We[i];
    if (tid < 64) att_s[tid] = att[tid];
    __syncthreads();

    const int w = tid >> 6, l = tid & 63;
    const int t0 = (l & 15) * 4;            // channel group
    const int e0 = w * 32 + (l >> 4) * 8;   // edge group (8 edges)

    float z[8][4];
#pragma unroll
    for (int j = 0; j < 8; ++j)
#pragma unroll
        for (int i = 0; i < 4; ++i) z[j][i] = 0.f;

#pragma unroll 4
    for (int k = 0; k < 32; ++k) {
        const float4 ev0 = *(const float4*)&ea_T[k][e0];
        const float4 ev1 = *(const float4*)&ea_T[k][e0 + 4];
        const float4 wv = *(const float4*)&We_s[k * 64 + t0];
        const float ee[8] = {ev0.x, ev0.y, ev0.z, ev0.w, ev1.x, ev1.y, ev1.z, ev1.w};
        const float ww[4] = {wv.x, wv.y, wv.z, wv.w};
#pragma unroll
        for (int j = 0; j < 8; ++j)
#pragma unroll
            for (int i = 0; i < 4; ++i) z[j][i] += ee[j] * ww[i];
    }

    const float4 av = *(const float4*)&att_s[t0];
    const float aa[4] = {av.x, av.y, av.z, av.w};
    float v[8];
#pragma unroll
    for (int j = 0; j < 8; ++j) {
        const int eb = e0 + j;
        const int s = s_s[eb];
        const int d = d_s[eb];
        const float4 xlv = *(const float4*)&xl[(size_t)s * 64 + t0];
        const float4 xrv = *(const float4*)&xr[(size_t)d * 64 + t0];
        const float xll[4] = {xlv.x, xlv.y, xlv.z, xlv.w};
        const float xrr[4] = {xrv.x, xrv.y, xrv.z, xrv.w};
        float acc = 0.f;
#pragma unroll
        for (int i = 0; i < 4; ++i) {
            float zz = z[j][i] + xll[i] + xrr[i];
            zz = (zz > 0.f) ? zz : NEG_SLOPE * zz;
            acc += aa[i] * zz;
        }
        v[j] = acc;
    }
#pragma unroll
    for (int m = 1; m < 16; m <<= 1) {
#pragma unroll
        for (int j = 0; j < 8; ++j) v[j] += __shfl_xor(v[j], m);
    }
    if ((l & 15) == 0) {
#pragma unroll
        for (int j = 0; j < 8; ++j) {
            int ge = ge0 + e0 + j;
            if (ge < E) ex_sorted[sp_s[e0 + j]] = __expf(v[j]);
        }
    }
}

// ---------- self-loop scores ----------
__global__ __launch_bounds__(256) void k_loop_score(
    const float* __restrict__ xl, const float* __restrict__ xr,
    const float* __restrict__ loop_attr,
    const float* __restrict__ We, const float* __restrict__ att,
    int n, float* __restrict__ ex_loop) {
    __shared__ float We_s[32 * 64];
    __shared__ float ea_T[32][68];
    __shared__ float att_s[64];

    const int tid = threadIdx.x;
    const int ge0 = blockIdx.x * 64;

    for (int i = tid; i < 2048; i += 256) We_s[i] = We[i];
    if (tid < 64) att_s[tid] = att[tid];
    {
        int e = tid & 63;
        int k0 = (tid >> 6) * 8;
        int ge = ge0 + e;
        float4 a = make_float4(0.f, 0.f, 0.f, 0.f), b = a;
        if (ge < n) {
            const float4* p = (const float4*)(loop_attr + (size_t)ge * 32 + k0);
            a = p[0]; b = p[1];
        }
        ea_T[k0 + 0][e] = a.x; ea_T[k0 + 1][e] = a.y; ea_T[k0 + 2][e] = a.z; ea_T[k0 + 3][e] = a.w;
        ea_T[k0 + 4][e] = b.x; ea_T[k0 + 5][e] = b.y; ea_T[k0 + 6][e] = b.z; ea_T[k0 + 7][e] = b.w;
    }
    __syncthreads();

    const int w = tid >> 6, l = tid & 63;
    const int t0 = (l & 15) * 4;
    const int e0 = w * 16 + (l >> 4) * 4;

    float z[4][4];
#pragma unroll
    for (int j = 0; j < 4; ++j)
#pragma unroll
        for (int i = 0; i < 4; ++i) z[j][i] = 0.f;

#pragma unroll 8
    for (int k = 0; k < 32; ++k) {
        const float4 ev = *(const float4*)&ea_T[k][e0];
        const float4 wv = *(const float4*)&We_s[k * 64 + t0];
        const float ee[4] = {ev.x, ev.y, ev.z, ev.w};
        const float ww[4] = {wv.x, wv.y, wv.z, wv.w};
#pragma unroll
        for (int j = 0; j < 4; ++j)
#pragma unroll
            for (int i = 0; i < 4; ++i) z[j][i] += ee[j] * ww[i];
    }

    const float4 av = *(const float4*)&att_s[t0];
    const float aa[4] = {av.x, av.y, av.z, av.w};
    float v[4];
#pragma unroll
    for (int j = 0; j < 4; ++j) {
        const int node = ge0 + e0 + j;
        const int nsafe = (node < n) ? node : 0;
        const float4 xlv = *(const float4*)&xl[(size_t)nsafe * 64 + t0];
        const float4 xrv = *(const float4*)&xr[(size_t)nsafe * 64 + t0];
        const float xll[4] = {xlv.x, xlv.y, xlv.z, xlv.w};
        const float xrr[4] = {xrv.x, xrv.y, xrv.z, xrv.w};
        float acc = 0.f;
#pragma unroll
        for (int i = 0; i < 4; ++i) {
            float zz = z[j][i] + xll[i] + xrr[i];
            zz = (zz > 0.f) ? zz : NEG_SLOPE * zz;
            acc += aa[i] * zz;
        }
        v[j] = acc;
    }
#pragma unroll
    for (int m = 1; m < 16; m <<= 1) {
#pragma unroll
        for (int j = 0; j < 4; ++j) v[j] += __shfl_xor(v[j], m);
    }
    if ((l & 15) == 0) {
#pragma unroll
        for (int j = 0; j < 4; ++j) {
            int node = ge0 + e0 + j;
            if (node < n) ex_loop[node] = __expf(v[j]);
        }
    }
}

// ---------- phase B: gather-side aggregation + epilogue ----------
// wave per node; 16 lanes x float4 per xl row, 4 edge slots -> 8 rows in flight.
template <bool FINAL>
__global__ __launch_bounds__(256) void k_node_aggr(
    const float* __restrict__ xl, const int* __restrict__ start,
    const int* __restrict__ src_sorted, const float* __restrict__ ex_sorted,
    const float* __restrict__ ex_loop, const float* __restrict__ bias,
    const float* __restrict__ Wc, const float* __restrict__ bc,
    float* __restrict__ hout, int n) {
    int node = blockIdx.x * 4 + (threadIdx.x >> 6);
    int t = threadIdx.x & 63;
    if (node >= n) return;
    const int es = t >> 4;   // edge slot 0..3
    const int cg = t & 15;   // channel group (float4)
    int a = start[node], b = start[node + 1];

    float4 acc = make_float4(0.f, 0.f, 0.f, 0.f);
    float den = 0.f;
    if (es == 0) {
        float exl = ex_loop[node];
        const float4 xv = *(const float4*)&xl[(size_t)node * 64 + cg * 4];
        acc.x = exl * xv.x; acc.y = exl * xv.y; acc.z = exl * xv.z; acc.w = exl * xv.w;
        den = exl;
    }
    for (int j = a; j < b; j += 64) {
        int m = b - j; if (m > 64) m = 64;
        int sj = 0; float exj = 0.f;
        if (t < m) { sj = src_sorted[j + t]; exj = ex_sorted[j + t]; }
        for (int i = 0; i < m; i += 8) {
            const int i0 = i + es, i1 = i + 4 + es;
            const int s0 = __shfl(sj, i0); const float e0 = __shfl(exj, i0);
            const int s1 = __shfl(sj, i1); const float e1 = __shfl(exj, i1);
            if (i0 < m) {
                const float4 xv = *(const float4*)&xl[(size_t)s0 * 64 + cg * 4];
                acc.x += e0 * xv.x; acc.y += e0 * xv.y;
                acc.z += e0 * xv.z; acc.w += e0 * xv.w;
                den += e0;
            }
            if (i1 < m) {
                const float4 xv = *(const float4*)&xl[(size_t)s1 * 64 + cg * 4];
                acc.x += e1 * xv.x; acc.y += e1 * xv.y;
                acc.z += e1 * xv.z; acc.w += e1 * xv.w;
                den += e1;
            }
        }
    }
#pragma unroll
    for (int mask = 16; mask <= 32; mask <<= 1) {
        acc.x += __shfl_xor(acc.x, mask);
        acc.y += __shfl_xor(acc.y, mask);
        acc.z += __shfl_xor(acc.z, mask);
        acc.w += __shfl_xor(acc.w, mask);
        den   += __shfl_xor(den, mask);
    }
    if (!FINAL) {
        if (es == 0) {
            const float4 bv = *(const float4*)&bias[cg * 4];
            float4 h;
            h.x = fmaxf(acc.x / den + bv.x, 0.f);
            h.y = fmaxf(acc.y / den + bv.y, 0.f);
            h.z = fmaxf(acc.z / den + bv.z, 0.f);
            h.w = fmaxf(acc.w / den + bv.w, 0.f);
            *(float4*)&hout[(size_t)node * 64 + cg * 4] = h;
        }
    } else {
        float v0 = 0.f, v1 = 0.f;
        if (es == 0) {
            const float4 bv = *(const float4*)&bias[cg * 4];
            const float h0 = fmaxf(acc.x / den + bv.x, 0.f);
            const float h1 = fmaxf(acc.y / den + bv.y, 0.f);
            const float h2 = fmaxf(acc.z / den + bv.z, 0.f);
            const float h3 = fmaxf(acc.w / den + bv.w, 0.f);
            const int c0 = cg * 4;
            v0 = h0 * Wc[(c0 + 0) * 2 + 0] + h1 * Wc[(c0 + 1) * 2 + 0]
               + h2 * Wc[(c0 + 2) * 2 + 0] + h3 * Wc[(c0 + 3) * 2 + 0];
            v1 = h0 * Wc[(c0 + 0) * 2 + 1] + h1 * Wc[(c0 + 1) * 2 + 1]
               + h2 * Wc[(c0 + 2) * 2 + 1] + h3 * Wc[(c0 + 3) * 2 + 1];
        }
#pragma unroll
        for (int mask = 1; mask <= 8; mask <<= 1) {
            v0 += __shfl_xor(v0, mask);
            v1 += __shfl_xor(v1, mask);
        }
        if (t == 0) {
            hout[(size_t)node * 2 + 0] = v0 + bc[0];
            hout[(size_t)node * 2 + 1] = v1 + bc[1];
        }
    }
}

extern "C" void kernel_launch(void* const* d_in, const int* in_sizes, int n_in,
                              void* d_out, int out_size, void* d_ws, size_t ws_size,
                              hipStream_t stream) {
    const float* x     = (const float*)d_in[0];
    const int*   ei    = (const int*)d_in[1];
    const float* eattr = (const float*)d_in[2];
    const float* Wl1 = (const float*)d_in[3];
    const float* bl1 = (const float*)d_in[4];
    const float* Wr1 = (const float*)d_in[5];
    const float* br1 = (const float*)d_in[6];
    const float* We1 = (const float*)d_in[7];
    const float* att1 = (const float*)d_in[8];
    const float* bias1 = (const float*)d_in[9];
    const float* Wl2 = (const float*)d_in[10];
    const float* bl2 = (const float*)d_in[11];
    const float* Wr2 = (const float*)d_in[12];
    const float* br2 = (const float*)d_in[13];
    const float* We2 = (const float*)d_in[14];
    const float* att2 = (const float*)d_in[15];
    const float* bias2 = (const float*)d_in[16];
    const float* Wc = (const float*)d_in[17];
    const float* bc = (const float*)d_in[18];

    const int N = in_sizes[0] / 128;
    const int E = in_sizes[1] / 2;
    const int* src = ei;
    const int* dst = ei + E;

    char* w = (char*)d_ws;
    auto alloc = [&](size_t bytes) {
        char* p = w;
        w += (bytes + 255) & ~(size_t)255;
        return p;
    };
    float* xl         = (float*)alloc((size_t)N * 64 * 4);
    float* xr         = (float*)alloc((size_t)N * 64 * 4);
    float* hbuf       = (float*)alloc((size_t)N * 64 * 4);
    float* loop_attr  = (float*)alloc((size_t)N * 32 * 4);
    float* ex_loop    = (float*)alloc((size_t)N * 4);
    int*   deg_i      = (int*)alloc((size_t)N * 4);
    int*   start      = (int*)alloc((size_t)(N + 1) * 4);
    int*   cursor     = (int*)alloc((size_t)N * 4);
    int*   perm       = (int*)alloc((size_t)E * 4);
    int*   src_sorted = (int*)alloc((size_t)E * 4);
    int*   sortpos    = (int*)alloc((size_t)E * 4);
    float* ex_sorted  = (float*)alloc((size_t)E * 4);

    const int THREADS = 256;
    const int score_blocks = (E + 127) / 128;
    const int loop_blocks = (N + 63) / 64;
    const int node4_blocks = (N + 3) / 4;
    const int edge_blocks = (E + THREADS - 1) / THREADS;

    // ---- CSR by dst (shared by both layers) ----
    hipMemsetAsync(deg_i, 0, (size_t)N * 4, stream);
    hipMemsetAsync(cursor, 0, (size_t)N * 4, stream);
    k_hist<<<edge_blocks, THREADS, 0, stream>>>(dst, E, deg_i);
    k_scan<<<1, 1024, 0, stream>>>(deg_i, start, N);
    k_fill<<<edge_blocks, THREADS, 0, stream>>>(src, dst, E, start, cursor,
                                                perm, src_sorted, sortpos);
    k_loop_csr<<<node4_blocks, THREADS, 0, stream>>>(eattr, perm, start, loop_attr, N);

    // ---- layer 1 ----
    k_node_transform<128><<<node4_blocks, THREADS, 0, stream>>>(x, Wl1, bl1, Wr1, br1, xl, xr, N);
    k_edge_score<<<score_blocks, THREADS, 0, stream>>>(
        xl, xr, eattr, We1, att1, src, dst, sortpos, E, ex_sorted);
    k_loop_score<<<loop_blocks, THREADS, 0, stream>>>(xl, xr, loop_attr, We1, att1, N, ex_loop);
    k_node_aggr<false><<<node4_blocks, THREADS, 0, stream>>>(xl, start, src_sorted, ex_sorted,
                                                             ex_loop, bias1, Wc, bc, hbuf, N);

    // ---- layer 2 ----
    k_node_transform<64><<<node4_blocks, THREADS, 0, stream>>>(hbuf, Wl2, bl2, Wr2, br2, xl, xr, N);
    k_loop_score<<<loop_blocks, THREADS, 0, stream>>>(xl, xr, loop_attr, We2, att2, N, ex_loop);
    k_edge_score<<<score_blocks, THREADS, 0, stream>>>(
        xl, xr, eattr, We2, att2, src, dst, sortpos, E, ex_sorted);
    k_node_aggr<true><<<node4_blocks, THREADS, 0, stream>>>(xl, start, src_sorted, ex_sorted,
                                                            ex_loop, bias2, Wc, bc, (float*)d_out, N);
}

// Round 10
// 850.768 us; speedup vs baseline: 2.1229x; 1.0301x over previous
//
#include <hip/hip_runtime.h>
#include <hip/hip_bf16.h>

#define NEG_SLOPE 0.2f

// ---------- CSR build ----------
__global__ void k_hist(const int* __restrict__ dst, int E, int* __restrict__ deg) {
    int e = blockIdx.x * 256 + threadIdx.x;
    if (e < E) atomicAdd(&deg[dst[e]], 1);
}

__global__ __launch_bounds__(1024) void k_scan(const int* __restrict__ deg,
                                               int* __restrict__ start, int n) {
    __shared__ int wsum[16];
    __shared__ int carry_s;
    if (threadIdx.x == 0) carry_s = 0;
    __syncthreads();
    const int lane = threadIdx.x & 63;
    const int w = threadIdx.x >> 6;
    for (int base = 0; base < n; base += 1024) {
        int i = base + (int)threadIdx.x;
        int v = (i < n) ? deg[i] : 0;
        int s = v;
#pragma unroll
        for (int o = 1; o < 64; o <<= 1) {
            int u = __shfl_up(s, o);
            if (lane >= o) s += u;
        }
        if (lane == 63) wsum[w] = s;
        __syncthreads();
        if (w == 0) {
            int ws = (lane < 16) ? wsum[lane] : 0;
#pragma unroll
            for (int o = 1; o < 16; o <<= 1) {
                int u = __shfl_up(ws, o);
                if (lane >= o) ws += u;
            }
            if (lane < 16) wsum[lane] = ws;
        }
        __syncthreads();
        int carry = carry_s;
        int woff = (w == 0) ? 0 : wsum[w - 1];
        int incl = s + woff + carry;
        if (i < n) start[i] = incl - v;
        __syncthreads();
        if (threadIdx.x == 1023) carry_s = incl;
        __syncthreads();
    }
    if (threadIdx.x == 0) start[n] = carry_s;
}

__global__ void k_fill(const int* __restrict__ src, const int* __restrict__ dst, int E,
                       const int* __restrict__ start, int* __restrict__ cursor,
                       int* __restrict__ perm, int* __restrict__ src_sorted,
                       int* __restrict__ sortpos) {
    int e = blockIdx.x * 256 + threadIdx.x;
    if (e >= E) return;
    int d = dst[e];
    int idx = start[d] + atomicAdd(&cursor[d], 1);
    perm[idx] = e;
    src_sorted[idx] = src[e];
    sortpos[e] = idx;
}

// ---------- self-loop attr: gather-side segment mean ----------
__global__ __launch_bounds__(256) void k_loop_csr(
    const float* __restrict__ eattr, const int* __restrict__ perm,
    const int* __restrict__ start, float* __restrict__ loop_attr, int n) {
    int node = blockIdx.x * 4 + (threadIdx.x >> 6);
    int t = threadIdx.x & 63;
    if (node >= n) return;
    int a = start[node], b = start[node + 1];
    int g = t >> 3, gl = t & 7;
    float4 acc = make_float4(0.f, 0.f, 0.f, 0.f);
    for (int j = a + g; j < b; j += 8) {
        int e = perm[j];
        const float4 v = *(const float4*)&eattr[(size_t)e * 32 + gl * 4];
        acc.x += v.x; acc.y += v.y; acc.z += v.z; acc.w += v.w;
    }
#pragma unroll
    for (int mask = 8; mask <= 32; mask <<= 1) {
        acc.x += __shfl_xor(acc.x, mask);
        acc.y += __shfl_xor(acc.y, mask);
        acc.z += __shfl_xor(acc.z, mask);
        acc.w += __shfl_xor(acc.w, mask);
    }
    if (t < 8) {
        float deg = fmaxf((float)(b - a), 1.f);
        float4 o = make_float4(acc.x / deg, acc.y / deg, acc.z / deg, acc.w / deg);
        *(float4*)&loop_attr[(size_t)node * 32 + gl * 4] = o;
    }
}

// ---------- node transform: xl = h@Wl+bl, xr = h@Wr+br ----------
template <int DIN>
__global__ void k_node_transform(const float* __restrict__ h,
                                 const float* __restrict__ Wl, const float* __restrict__ bl,
                                 const float* __restrict__ Wr, const float* __restrict__ br,
                                 float* __restrict__ xl, float* __restrict__ xr, int n) {
    __shared__ float hs[4][DIN];
    int node0 = blockIdx.x * 4;
    int tid = threadIdx.x;
    for (int idx = tid; idx < 4 * DIN; idx += 256) {
        int ln = idx / DIN, k = idx % DIN;
        int node = node0 + ln;
        hs[ln][k] = (node < n) ? h[(long long)node * DIN + k] : 0.f;
    }
    __syncthreads();
    int ln = tid >> 6;
    int j = tid & 63;
    int node = node0 + ln;
    if (node >= n) return;
    float al = bl[j], ar = br[j];
#pragma unroll 8
    for (int k = 0; k < DIN; ++k) {
        float hv = hs[ln][k];
        al += hv * Wl[k * 64 + j];
        ar += hv * Wr[k * 64 + j];
    }
    xl[(long long)node * 64 + j] = al;
    xr[(long long)node * 64 + j] = ar;
}

// ---------- phase A: edge scores, streaming order ----------
// 128 edges/block. ALL 16 xl/xr gathers issued BEFORE the GEMM loop so
// their ~400cy latency hides under the 32-k FMA work (vmcnt vs lgkmcnt
// are independent). __launch_bounds__(256,2) lifts the VGPR cap so the
// 16 float4 results stay in registers (R9's 44-VGPR build serialized them).
__global__ __launch_bounds__(256, 2) void k_edge_score(
    const float* __restrict__ xl, const float* __restrict__ xr,
    const float* __restrict__ eattr,
    const float* __restrict__ We, const float* __restrict__ att,
    const int* __restrict__ src, const int* __restrict__ dst,
    const int* __restrict__ sortpos, int E,
    float* __restrict__ ex_sorted) {
    __shared__ __align__(16) float We_s[32 * 64];
    __shared__ __align__(16) float ea_T[32][132];
    __shared__ float att_s[64];
    __shared__ int s_s[128], d_s[128], sp_s[128];

    const int tid = threadIdx.x;
    const int ge0 = blockIdx.x * 128;

    if (tid < 128) {
        int ge = ge0 + tid;
        bool ok = ge < E;
        s_s[tid] = ok ? src[ge] : 0;
        d_s[tid] = ok ? dst[ge] : 0;
        sp_s[tid] = ok ? sortpos[ge] : 0;
    }
    {
        const int e = tid & 127;
        const int kc = (tid >> 7) * 16;
        const int ge = ge0 + e;
        float4 a = make_float4(0.f, 0.f, 0.f, 0.f), b = a, c = a, d4 = a;
        if (ge < E) {
            const float4* p = (const float4*)(eattr + (size_t)ge * 32 + kc);
            a = p[0]; b = p[1]; c = p[2]; d4 = p[3];
        }
        ea_T[kc + 0][e] = a.x;  ea_T[kc + 1][e] = a.y;  ea_T[kc + 2][e] = a.z;  ea_T[kc + 3][e] = a.w;
        ea_T[kc + 4][e] = b.x;  ea_T[kc + 5][e] = b.y;  ea_T[kc + 6][e] = b.z;  ea_T[kc + 7][e] = b.w;
        ea_T[kc + 8][e] = c.x;  ea_T[kc + 9][e] = c.y;  ea_T[kc + 10][e] = c.z; ea_T[kc + 11][e] = c.w;
        ea_T[kc + 12][e] = d4.x; ea_T[kc + 13][e] = d4.y; ea_T[kc + 14][e] = d4.z; ea_T[kc + 15][e] = d4.w;
    }
    for (int i = tid; i < 2048; i += 256) We_s[i] = We[i];
    if (tid < 64) att_s[tid] = att[tid];
    __syncthreads();

    const int w = tid >> 6, l = tid & 63;
    const int t0 = (l & 15) * 4;            // channel group
    const int e0 = w * 32 + (l >> 4) * 8;   // edge group (8 edges)

    // issue ALL xl/xr gathers first — latency hides under the GEMM below
    float4 xlv[8], xrv[8];
#pragma unroll
    for (int j = 0; j < 8; ++j) {
        const int eb = e0 + j;
        xlv[j] = *(const float4*)&xl[(size_t)s_s[eb] * 64 + t0];
        xrv[j] = *(const float4*)&xr[(size_t)d_s[eb] * 64 + t0];
    }

    float z[8][4];
#pragma unroll
    for (int j = 0; j < 8; ++j)
#pragma unroll
        for (int i = 0; i < 4; ++i) z[j][i] = 0.f;

#pragma unroll 4
    for (int k = 0; k < 32; ++k) {
        const float4 ev0 = *(const float4*)&ea_T[k][e0];
        const float4 ev1 = *(const float4*)&ea_T[k][e0 + 4];
        const float4 wv = *(const float4*)&We_s[k * 64 + t0];
        const float ee[8] = {ev0.x, ev0.y, ev0.z, ev0.w, ev1.x, ev1.y, ev1.z, ev1.w};
        const float ww[4] = {wv.x, wv.y, wv.z, wv.w};
#pragma unroll
        for (int j = 0; j < 8; ++j)
#pragma unroll
            for (int i = 0; i < 4; ++i) z[j][i] += ee[j] * ww[i];
    }

    const float4 av = *(const float4*)&att_s[t0];
    const float aa[4] = {av.x, av.y, av.z, av.w};
    float v[8];
#pragma unroll
    for (int j = 0; j < 8; ++j) {
        const float xll[4] = {xlv[j].x, xlv[j].y, xlv[j].z, xlv[j].w};
        const float xrr[4] = {xrv[j].x, xrv[j].y, xrv[j].z, xrv[j].w};
        float acc = 0.f;
#pragma unroll
        for (int i = 0; i < 4; ++i) {
            float zz = z[j][i] + xll[i] + xrr[i];
            zz = (zz > 0.f) ? zz : NEG_SLOPE * zz;
            acc += aa[i] * zz;
        }
        v[j] = acc;
    }
#pragma unroll
    for (int m = 1; m < 16; m <<= 1) {
#pragma unroll
        for (int j = 0; j < 8; ++j) v[j] += __shfl_xor(v[j], m);
    }
    if ((l & 15) == 0) {
#pragma unroll
        for (int j = 0; j < 8; ++j) {
            int ge = ge0 + e0 + j;
            if (ge < E) ex_sorted[sp_s[e0 + j]] = __expf(v[j]);
        }
    }
}

// ---------- self-loop scores ----------
__global__ __launch_bounds__(256) void k_loop_score(
    const float* __restrict__ xl, const float* __restrict__ xr,
    const float* __restrict__ loop_attr,
    const float* __restrict__ We, const float* __restrict__ att,
    int n, float* __restrict__ ex_loop) {
    __shared__ float We_s[32 * 64];
    __shared__ float ea_T[32][68];
    __shared__ float att_s[64];

    const int tid = threadIdx.x;
    const int ge0 = blockIdx.x * 64;

    for (int i = tid; i < 2048; i += 256) We_s[i] = We[i];
    if (tid < 64) att_s[tid] = att[tid];
    {
        int e = tid & 63;
        int k0 = (tid >> 6) * 8;
        int ge = ge0 + e;
        float4 a = make_float4(0.f, 0.f, 0.f, 0.f), b = a;
        if (ge < n) {
            const float4* p = (const float4*)(loop_attr + (size_t)ge * 32 + k0);
            a = p[0]; b = p[1];
        }
        ea_T[k0 + 0][e] = a.x; ea_T[k0 + 1][e] = a.y; ea_T[k0 + 2][e] = a.z; ea_T[k0 + 3][e] = a.w;
        ea_T[k0 + 4][e] = b.x; ea_T[k0 + 5][e] = b.y; ea_T[k0 + 6][e] = b.z; ea_T[k0 + 7][e] = b.w;
    }
    __syncthreads();

    const int w = tid >> 6, l = tid & 63;
    const int t0 = (l & 15) * 4;
    const int e0 = w * 16 + (l >> 4) * 4;

    float z[4][4];
#pragma unroll
    for (int j = 0; j < 4; ++j)
#pragma unroll
        for (int i = 0; i < 4; ++i) z[j][i] = 0.f;

#pragma unroll 8
    for (int k = 0; k < 32; ++k) {
        const float4 ev = *(const float4*)&ea_T[k][e0];
        const float4 wv = *(const float4*)&We_s[k * 64 + t0];
        const float ee[4] = {ev.x, ev.y, ev.z, ev.w};
        const float ww[4] = {wv.x, wv.y, wv.z, wv.w};
#pragma unroll
        for (int j = 0; j < 4; ++j)
#pragma unroll
            for (int i = 0; i < 4; ++i) z[j][i] += ee[j] * ww[i];
    }

    const float4 av = *(const float4*)&att_s[t0];
    const float aa[4] = {av.x, av.y, av.z, av.w};
    float v[4];
#pragma unroll
    for (int j = 0; j < 4; ++j) {
        const int node = ge0 + e0 + j;
        const int nsafe = (node < n) ? node : 0;
        const float4 xlv = *(const float4*)&xl[(size_t)nsafe * 64 + t0];
        const float4 xrv = *(const float4*)&xr[(size_t)nsafe * 64 + t0];
        const float xll[4] = {xlv.x, xlv.y, xlv.z, xlv.w};
        const float xrr[4] = {xrv.x, xrv.y, xrv.z, xrv.w};
        float acc = 0.f;
#pragma unroll
        for (int i = 0; i < 4; ++i) {
            float zz = z[j][i] + xll[i] + xrr[i];
            zz = (zz > 0.f) ? zz : NEG_SLOPE * zz;
            acc += aa[i] * zz;
        }
        v[j] = acc;
    }
#pragma unroll
    for (int m = 1; m < 16; m <<= 1) {
#pragma unroll
        for (int j = 0; j < 4; ++j) v[j] += __shfl_xor(v[j], m);
    }
    if ((l & 15) == 0) {
#pragma unroll
        for (int j = 0; j < 4; ++j) {
            int node = ge0 + e0 + j;
            if (node < n) ex_loop[node] = __expf(v[j]);
        }
    }
}

// ---------- phase B: gather-side aggregation + epilogue ----------
// wave per node; 16 lanes x float4 per xl row, 4 edge slots x 4-deep
// pipeline -> 16 rows in flight per wave. launch_bounds(256,2) lets the
// compiler keep them in registers.
template <bool FINAL>
__global__ __launch_bounds__(256, 2) void k_node_aggr(
    const float* __restrict__ xl, const int* __restrict__ start,
    const int* __restrict__ src_sorted, const float* __restrict__ ex_sorted,
    const float* __restrict__ ex_loop, const float* __restrict__ bias,
    const float* __restrict__ Wc, const float* __restrict__ bc,
    float* __restrict__ hout, int n) {
    int node = blockIdx.x * 4 + (threadIdx.x >> 6);
    int t = threadIdx.x & 63;
    if (node >= n) return;
    const int es = t >> 4;   // edge slot 0..3
    const int cg = t & 15;   // channel group (float4)
    int a = start[node], b = start[node + 1];

    float4 acc = make_float4(0.f, 0.f, 0.f, 0.f);
    float den = 0.f;
    if (es == 0) {
        float exl = ex_loop[node];
        const float4 xv = *(const float4*)&xl[(size_t)node * 64 + cg * 4];
        acc.x = exl * xv.x; acc.y = exl * xv.y; acc.z = exl * xv.z; acc.w = exl * xv.w;
        den = exl;
    }
    for (int j = a; j < b; j += 64) {
        int m = b - j; if (m > 64) m = 64;
        int sj = 0; float exj = 0.f;
        if (t < m) { sj = src_sorted[j + t]; exj = ex_sorted[j + t]; }
        for (int i = 0; i < m; i += 16) {
            int idx[4]; float ex4[4]; const float4* p4[4];
#pragma unroll
            for (int q = 0; q < 4; ++q) {
                idx[q] = i + q * 4 + es;
                const int sq = __shfl(sj, idx[q]);
                ex4[q] = __shfl(exj, idx[q]);
                p4[q] = (const float4*)&xl[(size_t)sq * 64 + cg * 4];
            }
            float4 xv[4];
#pragma unroll
            for (int q = 0; q < 4; ++q)
                xv[q] = (idx[q] < m) ? *p4[q] : make_float4(0.f, 0.f, 0.f, 0.f);
#pragma unroll
            for (int q = 0; q < 4; ++q) {
                const float eq = (idx[q] < m) ? ex4[q] : 0.f;
                acc.x += eq * xv[q].x; acc.y += eq * xv[q].y;
                acc.z += eq * xv[q].z; acc.w += eq * xv[q].w;
                den += eq;
            }
        }
    }
#pragma unroll
    for (int mask = 16; mask <= 32; mask <<= 1) {
        acc.x += __shfl_xor(acc.x, mask);
        acc.y += __shfl_xor(acc.y, mask);
        acc.z += __shfl_xor(acc.z, mask);
        acc.w += __shfl_xor(acc.w, mask);
        den   += __shfl_xor(den, mask);
    }
    if (!FINAL) {
        if (es == 0) {
            const float4 bv = *(const float4*)&bias[cg * 4];
            float4 h;
            h.x = fmaxf(acc.x / den + bv.x, 0.f);
            h.y = fmaxf(acc.y / den + bv.y, 0.f);
            h.z = fmaxf(acc.z / den + bv.z, 0.f);
            h.w = fmaxf(acc.w / den + bv.w, 0.f);
            *(float4*)&hout[(size_t)node * 64 + cg * 4] = h;
        }
    } else {
        float v0 = 0.f, v1 = 0.f;
        if (es == 0) {
            const float4 bv = *(const float4*)&bias[cg * 4];
            const float h0 = fmaxf(acc.x / den + bv.x, 0.f);
            const float h1 = fmaxf(acc.y / den + bv.y, 0.f);
            const float h2 = fmaxf(acc.z / den + bv.z, 0.f);
            const float h3 = fmaxf(acc.w / den + bv.w, 0.f);
            const int c0 = cg * 4;
            v0 = h0 * Wc[(c0 + 0) * 2 + 0] + h1 * Wc[(c0 + 1) * 2 + 0]
               + h2 * Wc[(c0 + 2) * 2 + 0] + h3 * Wc[(c0 + 3) * 2 + 0];
            v1 = h0 * Wc[(c0 + 0) * 2 + 1] + h1 * Wc[(c0 + 1) * 2 + 1]
               + h2 * Wc[(c0 + 2) * 2 + 1] + h3 * Wc[(c0 + 3) * 2 + 1];
        }
#pragma unroll
        for (int mask = 1; mask <= 8; mask <<= 1) {
            v0 += __shfl_xor(v0, mask);
            v1 += __shfl_xor(v1, mask);
        }
        if (t == 0) {
            hout[(size_t)node * 2 + 0] = v0 + bc[0];
            hout[(size_t)node * 2 + 1] = v1 + bc[1];
        }
    }
}

extern "C" void kernel_launch(void* const* d_in, const int* in_sizes, int n_in,
                              void* d_out, int out_size, void* d_ws, size_t ws_size,
                              hipStream_t stream) {
    const float* x     = (const float*)d_in[0];
    const int*   ei    = (const int*)d_in[1];
    const float* eattr = (const float*)d_in[2];
    const float* Wl1 = (const float*)d_in[3];
    const float* bl1 = (const float*)d_in[4];
    const float* Wr1 = (const float*)d_in[5];
    const float* br1 = (const float*)d_in[6];
    const float* We1 = (const float*)d_in[7];
    const float* att1 = (const float*)d_in[8];
    const float* bias1 = (const float*)d_in[9];
    const float* Wl2 = (const float*)d_in[10];
    const float* bl2 = (const float*)d_in[11];
    const float* Wr2 = (const float*)d_in[12];
    const float* br2 = (const float*)d_in[13];
    const float* We2 = (const float*)d_in[14];
    const float* att2 = (const float*)d_in[15];
    const float* bias2 = (const float*)d_in[16];
    const float* Wc = (const float*)d_in[17];
    const float* bc = (const float*)d_in[18];

    const int N = in_sizes[0] / 128;
    const int E = in_sizes[1] / 2;
    const int* src = ei;
    const int* dst = ei + E;

    char* w = (char*)d_ws;
    auto alloc = [&](size_t bytes) {
        char* p = w;
        w += (bytes + 255) & ~(size_t)255;
        return p;
    };
    float* xl         = (float*)alloc((size_t)N * 64 * 4);
    float* xr         = (float*)alloc((size_t)N * 64 * 4);
    float* hbuf       = (float*)alloc((size_t)N * 64 * 4);
    float* loop_attr  = (float*)alloc((size_t)N * 32 * 4);
    float* ex_loop    = (float*)alloc((size_t)N * 4);
    int*   deg_i      = (int*)alloc((size_t)N * 4);
    int*   start      = (int*)alloc((size_t)(N + 1) * 4);
    int*   cursor     = (int*)alloc((size_t)N * 4);
    int*   perm       = (int*)alloc((size_t)E * 4);
    int*   src_sorted = (int*)alloc((size_t)E * 4);
    int*   sortpos    = (int*)alloc((size_t)E * 4);
    float* ex_sorted  = (float*)alloc((size_t)E * 4);

    const int THREADS = 256;
    const int score_blocks = (E + 127) / 128;
    const int loop_blocks = (N + 63) / 64;
    const int node4_blocks = (N + 3) / 4;
    const int edge_blocks = (E + THREADS - 1) / THREADS;

    // ---- CSR by dst (shared by both layers) ----
    hipMemsetAsync(deg_i, 0, (size_t)N * 4, stream);
    hipMemsetAsync(cursor, 0, (size_t)N * 4, stream);
    k_hist<<<edge_blocks, THREADS, 0, stream>>>(dst, E, deg_i);
    k_scan<<<1, 1024, 0, stream>>>(deg_i, start, N);
    k_fill<<<edge_blocks, THREADS, 0, stream>>>(src, dst, E, start, cursor,
                                                perm, src_sorted, sortpos);
    k_loop_csr<<<node4_blocks, THREADS, 0, stream>>>(eattr, perm, start, loop_attr, N);

    // ---- layer 1 ----
    k_node_transform<128><<<node4_blocks, THREADS, 0, stream>>>(x, Wl1, bl1, Wr1, br1, xl, xr, N);
    k_edge_score<<<score_blocks, THREADS, 0, stream>>>(
        xl, xr, eattr, We1, att1, src, dst, sortpos, E, ex_sorted);
    k_loop_score<<<loop_blocks, THREADS, 0, stream>>>(xl, xr, loop_attr, We1, att1, N, ex_loop);
    k_node_aggr<false><<<node4_blocks, THREADS, 0, stream>>>(xl, start, src_sorted, ex_sorted,
                                                             ex_loop, bias1, Wc, bc, hbuf, N);

    // ---- layer 2 ----
    k_node_transform<64><<<node4_blocks, THREADS, 0, stream>>>(hbuf, Wl2, bl2, Wr2, br2, xl, xr, N);
    k_loop_score<<<loop_blocks, THREADS, 0, stream>>>(xl, xr, loop_attr, We2, att2, N, ex_loop);
    k_edge_score<<<score_blocks, THREADS, 0, stream>>>(
        xl, xr, eattr, We2, att2, src, dst, sortpos, E, ex_sorted);
    k_node_aggr<true><<<node4_blocks, THREADS, 0, stream>>>(xl, start, src_sorted, ex_sorted,
                                                            ex_loop, bias2, Wc, bc, (float*)d_out, N);
}

// Round 11
// 767.676 us; speedup vs baseline: 2.3527x; 1.1082x over previous
//
#include <hip/hip_runtime.h>
#include <hip/hip_bf16.h>

#define NEG_SLOPE 0.2f

__device__ __forceinline__ float bf2f(unsigned short u) {
    return __uint_as_float((unsigned)u << 16);
}
__device__ __forceinline__ unsigned short f2bf(float f) {
    unsigned b = __float_as_uint(f);
    return (unsigned short)((b + 0x7FFFu + ((b >> 16) & 1u)) >> 16);
}

// ---------- CSR build ----------
__global__ void k_hist(const int* __restrict__ dst, int E, int* __restrict__ deg) {
    int e = blockIdx.x * 256 + threadIdx.x;
    if (e < E) atomicAdd(&deg[dst[e]], 1);
}

// hierarchical exclusive scan: chunk scan (1024/block) -> 1-wave top -> apply
__global__ __launch_bounds__(1024) void k_scan_chunk(const int* __restrict__ deg,
                                                     int* __restrict__ start,
                                                     int* __restrict__ csum, int n) {
    __shared__ int wsum[16];
    const int lane = threadIdx.x & 63;
    const int w = threadIdx.x >> 6;
    int i = blockIdx.x * 1024 + (int)threadIdx.x;
    int v = (i < n) ? deg[i] : 0;
    int s = v;
#pragma unroll
    for (int o = 1; o < 64; o <<= 1) {
        int u = __shfl_up(s, o);
        if (lane >= o) s += u;
    }
    if (lane == 63) wsum[w] = s;
    __syncthreads();
    if (w == 0) {
        int ws = (lane < 16) ? wsum[lane] : 0;
#pragma unroll
        for (int o = 1; o < 16; o <<= 1) {
            int u = __shfl_up(ws, o);
            if (lane >= o) ws += u;
        }
        if (lane < 16) wsum[lane] = ws;
    }
    __syncthreads();
    int woff = (w == 0) ? 0 : wsum[w - 1];
    int incl = s + woff;
    if (i < n) start[i] = incl - v;
    if (threadIdx.x == 1023) csum[blockIdx.x] = incl;
}

__global__ void k_scan_top(int* __restrict__ csum, int nch, int* __restrict__ start, int n) {
    int t = threadIdx.x;   // 64 threads, nch <= 64
    int v = (t < nch) ? csum[t] : 0;
    int s = v;
#pragma unroll
    for (int o = 1; o < 64; o <<= 1) {
        int u = __shfl_up(s, o);
        if (t >= o) s += u;
    }
    if (t < nch) csum[t] = s - v;   // exclusive chunk offsets
    if (t == 63) start[n] = s;      // grand total
}

__global__ void k_scan_apply(int* __restrict__ start, const int* __restrict__ csum, int n) {
    int i = blockIdx.x * 256 + threadIdx.x;
    if (i < n) start[i] += csum[i >> 10];
}

__global__ void k_fill(const int* __restrict__ src, const int* __restrict__ dst, int E,
                       const int* __restrict__ start, int* __restrict__ cursor,
                       int* __restrict__ perm, int* __restrict__ src_sorted,
                       int* __restrict__ sortpos) {
    int e = blockIdx.x * 256 + threadIdx.x;
    if (e >= E) return;
    int d = dst[e];
    int idx = start[d] + atomicAdd(&cursor[d], 1);
    perm[idx] = e;
    src_sorted[idx] = src[e];
    sortpos[e] = idx;
}

// ---------- self-loop attr: gather-side segment mean, 16 rows in flight ----------
__global__ __launch_bounds__(256) void k_loop_csr(
    const float* __restrict__ eattr, const int* __restrict__ perm,
    const int* __restrict__ start, float* __restrict__ loop_attr, int n) {
    int node = blockIdx.x * 4 + (threadIdx.x >> 6);
    int t = threadIdx.x & 63;
    if (node >= n) return;
    int a = start[node], b = start[node + 1];
    int g = t >> 3, gl = t & 7;
    float4 acc = make_float4(0.f, 0.f, 0.f, 0.f);
    int j = a + g;
    for (; j + 8 < b; j += 16) {
        int e1 = perm[j];
        int e2 = perm[j + 8];
        const float4 v1 = *(const float4*)&eattr[(size_t)e1 * 32 + gl * 4];
        const float4 v2 = *(const float4*)&eattr[(size_t)e2 * 32 + gl * 4];
        acc.x += v1.x + v2.x; acc.y += v1.y + v2.y;
        acc.z += v1.z + v2.z; acc.w += v1.w + v2.w;
    }
    if (j < b) {
        int e = perm[j];
        const float4 v = *(const float4*)&eattr[(size_t)e * 32 + gl * 4];
        acc.x += v.x; acc.y += v.y; acc.z += v.z; acc.w += v.w;
    }
#pragma unroll
    for (int mask = 8; mask <= 32; mask <<= 1) {
        acc.x += __shfl_xor(acc.x, mask);
        acc.y += __shfl_xor(acc.y, mask);
        acc.z += __shfl_xor(acc.z, mask);
        acc.w += __shfl_xor(acc.w, mask);
    }
    if (t < 8) {
        float deg = fmaxf((float)(b - a), 1.f);
        float4 o = make_float4(acc.x / deg, acc.y / deg, acc.z / deg, acc.w / deg);
        *(float4*)&loop_attr[(size_t)node * 32 + gl * 4] = o;
    }
}

// ---------- node transform: xl(fp32) + xlb,xrb(bf16 score tables) ----------
template <int DIN>
__global__ void k_node_transform(const float* __restrict__ h,
                                 const float* __restrict__ Wl, const float* __restrict__ bl,
                                 const float* __restrict__ Wr, const float* __restrict__ br,
                                 float* __restrict__ xl, unsigned short* __restrict__ xlb,
                                 unsigned short* __restrict__ xrb, int n) {
    __shared__ float hs[4][DIN];
    int node0 = blockIdx.x * 4;
    int tid = threadIdx.x;
    for (int idx = tid; idx < 4 * DIN; idx += 256) {
        int ln = idx / DIN, k = idx % DIN;
        int node = node0 + ln;
        hs[ln][k] = (node < n) ? h[(long long)node * DIN + k] : 0.f;
    }
    __syncthreads();
    int ln = tid >> 6;
    int j = tid & 63;
    int node = node0 + ln;
    if (node >= n) return;
    float al = bl[j], ar = br[j];
#pragma unroll 8
    for (int k = 0; k < DIN; ++k) {
        float hv = hs[ln][k];
        al += hv * Wl[k * 64 + j];
        ar += hv * Wr[k * 64 + j];
    }
    xl[(long long)node * 64 + j] = al;
    xlb[(long long)node * 64 + j] = f2bf(al);
    xrb[(long long)node * 64 + j] = f2bf(ar);
}

// ---------- phase A: edge scores, streaming order, bf16 gather tables ----------
__global__ __launch_bounds__(256, 2) void k_edge_score(
    const unsigned short* __restrict__ xlb, const unsigned short* __restrict__ xrb,
    const float* __restrict__ eattr,
    const float* __restrict__ We, const float* __restrict__ att,
    const int* __restrict__ src, const int* __restrict__ dst,
    const int* __restrict__ sortpos, int E,
    float* __restrict__ ex_sorted) {
    __shared__ __align__(16) float We_s[32 * 64];
    __shared__ __align__(16) float ea_T[32][132];
    __shared__ float att_s[64];
    __shared__ int s_s[128], d_s[128], sp_s[128];

    const int tid = threadIdx.x;
    const int ge0 = blockIdx.x * 128;

    if (tid < 128) {
        int ge = ge0 + tid;
        bool ok = ge < E;
        s_s[tid] = ok ? src[ge] : 0;
        d_s[tid] = ok ? dst[ge] : 0;
        sp_s[tid] = ok ? sortpos[ge] : 0;
    }
    {
        const int e = tid & 127;
        const int kc = (tid >> 7) * 16;
        const int ge = ge0 + e;
        float4 a = make_float4(0.f, 0.f, 0.f, 0.f), b = a, c = a, d4 = a;
        if (ge < E) {
            const float4* p = (const float4*)(eattr + (size_t)ge * 32 + kc);
            a = p[0]; b = p[1]; c = p[2]; d4 = p[3];
        }
        ea_T[kc + 0][e] = a.x;  ea_T[kc + 1][e] = a.y;  ea_T[kc + 2][e] = a.z;  ea_T[kc + 3][e] = a.w;
        ea_T[kc + 4][e] = b.x;  ea_T[kc + 5][e] = b.y;  ea_T[kc + 6][e] = b.z;  ea_T[kc + 7][e] = b.w;
        ea_T[kc + 8][e] = c.x;  ea_T[kc + 9][e] = c.y;  ea_T[kc + 10][e] = c.z; ea_T[kc + 11][e] = c.w;
        ea_T[kc + 12][e] = d4.x; ea_T[kc + 13][e] = d4.y; ea_T[kc + 14][e] = d4.z; ea_T[kc + 15][e] = d4.w;
    }
    for (int i = tid; i < 2048; i += 256) We_s[i] = We[i];
    if (tid < 64) att_s[tid] = att[tid];
    __syncthreads();

    const int w = tid >> 6, l = tid & 63;
    const int t0 = (l & 15) * 4;            // channel group
    const int e0 = w * 32 + (l >> 4) * 8;   // edge group (8 edges)

    // issue all gathers first (8B/lane bf16) — hide under the GEMM
    ushort4 xlv[8], xrv[8];
#pragma unroll
    for (int j = 0; j < 8; ++j) {
        const int eb = e0 + j;
        xlv[j] = *(const ushort4*)&xlb[(size_t)s_s[eb] * 64 + t0];
        xrv[j] = *(const ushort4*)&xrb[(size_t)d_s[eb] * 64 + t0];
    }

    float z[8][4];
#pragma unroll
    for (int j = 0; j < 8; ++j)
#pragma unroll
        for (int i = 0; i < 4; ++i) z[j][i] = 0.f;

#pragma unroll 4
    for (int k = 0; k < 32; ++k) {
        const float4 ev0 = *(const float4*)&ea_T[k][e0];
        const float4 ev1 = *(const float4*)&ea_T[k][e0 + 4];
        const float4 wv = *(const float4*)&We_s[k * 64 + t0];
        const float ee[8] = {ev0.x, ev0.y, ev0.z, ev0.w, ev1.x, ev1.y, ev1.z, ev1.w};
        const float ww[4] = {wv.x, wv.y, wv.z, wv.w};
#pragma unroll
        for (int j = 0; j < 8; ++j)
#pragma unroll
            for (int i = 0; i < 4; ++i) z[j][i] += ee[j] * ww[i];
    }

    const float4 av = *(const float4*)&att_s[t0];
    const float aa[4] = {av.x, av.y, av.z, av.w};
    float v[8];
#pragma unroll
    for (int j = 0; j < 8; ++j) {
        const float xll[4] = {bf2f(xlv[j].x), bf2f(xlv[j].y), bf2f(xlv[j].z), bf2f(xlv[j].w)};
        const float xrr[4] = {bf2f(xrv[j].x), bf2f(xrv[j].y), bf2f(xrv[j].z), bf2f(xrv[j].w)};
        float acc = 0.f;
#pragma unroll
        for (int i = 0; i < 4; ++i) {
            float zz = z[j][i] + xll[i] + xrr[i];
            zz = (zz > 0.f) ? zz : NEG_SLOPE * zz;
            acc += aa[i] * zz;
        }
        v[j] = acc;
    }
#pragma unroll
    for (int m = 1; m < 16; m <<= 1) {
#pragma unroll
        for (int j = 0; j < 8; ++j) v[j] += __shfl_xor(v[j], m);
    }
    if ((l & 15) == 0) {
#pragma unroll
        for (int j = 0; j < 8; ++j) {
            int ge = ge0 + e0 + j;
            if (ge < E) ex_sorted[sp_s[e0 + j]] = __expf(v[j]);
        }
    }
}

// ---------- self-loop scores (bf16 x tables) ----------
__global__ __launch_bounds__(256) void k_loop_score(
    const unsigned short* __restrict__ xlb, const unsigned short* __restrict__ xrb,
    const float* __restrict__ loop_attr,
    const float* __restrict__ We, const float* __restrict__ att,
    int n, float* __restrict__ ex_loop) {
    __shared__ float We_s[32 * 64];
    __shared__ float ea_T[32][68];
    __shared__ float att_s[64];

    const int tid = threadIdx.x;
    const int ge0 = blockIdx.x * 64;

    for (int i = tid; i < 2048; i += 256) We_s[i] = We[i];
    if (tid < 64) att_s[tid] = att[tid];
    {
        int e = tid & 63;
        int k0 = (tid >> 6) * 8;
        int ge = ge0 + e;
        float4 a = make_float4(0.f, 0.f, 0.f, 0.f), b = a;
        if (ge < n) {
            const float4* p = (const float4*)(loop_attr + (size_t)ge * 32 + k0);
            a = p[0]; b = p[1];
        }
        ea_T[k0 + 0][e] = a.x; ea_T[k0 + 1][e] = a.y; ea_T[k0 + 2][e] = a.z; ea_T[k0 + 3][e] = a.w;
        ea_T[k0 + 4][e] = b.x; ea_T[k0 + 5][e] = b.y; ea_T[k0 + 6][e] = b.z; ea_T[k0 + 7][e] = b.w;
    }
    __syncthreads();

    const int w = tid >> 6, l = tid & 63;
    const int t0 = (l & 15) * 4;
    const int e0 = w * 16 + (l >> 4) * 4;

    float z[4][4];
#pragma unroll
    for (int j = 0; j < 4; ++j)
#pragma unroll
        for (int i = 0; i < 4; ++i) z[j][i] = 0.f;

#pragma unroll 8
    for (int k = 0; k < 32; ++k) {
        const float4 ev = *(const float4*)&ea_T[k][e0];
        const float4 wv = *(const float4*)&We_s[k * 64 + t0];
        const float ee[4] = {ev.x, ev.y, ev.z, ev.w};
        const float ww[4] = {wv.x, wv.y, wv.z, wv.w};
#pragma unroll
        for (int j = 0; j < 4; ++j)
#pragma unroll
            for (int i = 0; i < 4; ++i) z[j][i] += ee[j] * ww[i];
    }

    const float4 av = *(const float4*)&att_s[t0];
    const float aa[4] = {av.x, av.y, av.z, av.w};
    float v[4];
#pragma unroll
    for (int j = 0; j < 4; ++j) {
        const int node = ge0 + e0 + j;
        const int nsafe = (node < n) ? node : 0;
        const ushort4 xlv = *(const ushort4*)&xlb[(size_t)nsafe * 64 + t0];
        const ushort4 xrv = *(const ushort4*)&xrb[(size_t)nsafe * 64 + t0];
        const float xll[4] = {bf2f(xlv.x), bf2f(xlv.y), bf2f(xlv.z), bf2f(xlv.w)};
        const float xrr[4] = {bf2f(xrv.x), bf2f(xrv.y), bf2f(xrv.z), bf2f(xrv.w)};
        float acc = 0.f;
#pragma unroll
        for (int i = 0; i < 4; ++i) {
            float zz = z[j][i] + xll[i] + xrr[i];
            zz = (zz > 0.f) ? zz : NEG_SLOPE * zz;
            acc += aa[i] * zz;
        }
        v[j] = acc;
    }
#pragma unroll
    for (int m = 1; m < 16; m <<= 1) {
#pragma unroll
        for (int j = 0; j < 4; ++j) v[j] += __shfl_xor(v[j], m);
    }
    if ((l & 15) == 0) {
#pragma unroll
        for (int j = 0; j < 4; ++j) {
            int node = ge0 + e0 + j;
            if (node < n) ex_loop[node] = __expf(v[j]);
        }
    }
}

// ---------- phase B: gather-side aggregation + epilogue ----------
template <bool FINAL>
__global__ __launch_bounds__(256, 2) void k_node_aggr(
    const float* __restrict__ xl, const int* __restrict__ start,
    const int* __restrict__ src_sorted, const float* __restrict__ ex_sorted,
    const float* __restrict__ ex_loop, const float* __restrict__ bias,
    const float* __restrict__ Wc, const float* __restrict__ bc,
    float* __restrict__ hout, int n) {
    int node = blockIdx.x * 4 + (threadIdx.x >> 6);
    int t = threadIdx.x & 63;
    if (node >= n) return;
    const int es = t >> 4;   // edge slot 0..3
    const int cg = t & 15;   // channel group (float4)
    int a = start[node], b = start[node + 1];

    float4 acc = make_float4(0.f, 0.f, 0.f, 0.f);
    float den = 0.f;
    if (es == 0) {
        float exl = ex_loop[node];
        const float4 xv = *(const float4*)&xl[(size_t)node * 64 + cg * 4];
        acc.x = exl * xv.x; acc.y = exl * xv.y; acc.z = exl * xv.z; acc.w = exl * xv.w;
        den = exl;
    }
    for (int j = a; j < b; j += 64) {
        int m = b - j; if (m > 64) m = 64;
        int sj = 0; float exj = 0.f;
        if (t < m) { sj = src_sorted[j + t]; exj = ex_sorted[j + t]; }
        for (int i = 0; i < m; i += 16) {
            int idx[4]; float ex4[4]; const float4* p4[4];
#pragma unroll
            for (int q = 0; q < 4; ++q) {
                idx[q] = i + q * 4 + es;
                const int sq = __shfl(sj, idx[q]);
                ex4[q] = __shfl(exj, idx[q]);
                p4[q] = (const float4*)&xl[(size_t)sq * 64 + cg * 4];
            }
            float4 xv[4];
#pragma unroll
            for (int q = 0; q < 4; ++q)
                xv[q] = (idx[q] < m) ? *p4[q] : make_float4(0.f, 0.f, 0.f, 0.f);
#pragma unroll
            for (int q = 0; q < 4; ++q) {
                const float eq = (idx[q] < m) ? ex4[q] : 0.f;
                acc.x += eq * xv[q].x; acc.y += eq * xv[q].y;
                acc.z += eq * xv[q].z; acc.w += eq * xv[q].w;
                den += eq;
            }
        }
    }
#pragma unroll
    for (int mask = 16; mask <= 32; mask <<= 1) {
        acc.x += __shfl_xor(acc.x, mask);
        acc.y += __shfl_xor(acc.y, mask);
        acc.z += __shfl_xor(acc.z, mask);
        acc.w += __shfl_xor(acc.w, mask);
        den   += __shfl_xor(den, mask);
    }
    if (!FINAL) {
        if (es == 0) {
            const float4 bv = *(const float4*)&bias[cg * 4];
            float4 h;
            h.x = fmaxf(acc.x / den + bv.x, 0.f);
            h.y = fmaxf(acc.y / den + bv.y, 0.f);
            h.z = fmaxf(acc.z / den + bv.z, 0.f);
            h.w = fmaxf(acc.w / den + bv.w, 0.f);
            *(float4*)&hout[(size_t)node * 64 + cg * 4] = h;
        }
    } else {
        float v0 = 0.f, v1 = 0.f;
        if (es == 0) {
            const float4 bv = *(const float4*)&bias[cg * 4];
            const float h0 = fmaxf(acc.x / den + bv.x, 0.f);
            const float h1 = fmaxf(acc.y / den + bv.y, 0.f);
            const float h2 = fmaxf(acc.z / den + bv.z, 0.f);
            const float h3 = fmaxf(acc.w / den + bv.w, 0.f);
            const int c0 = cg * 4;
            v0 = h0 * Wc[(c0 + 0) * 2 + 0] + h1 * Wc[(c0 + 1) * 2 + 0]
               + h2 * Wc[(c0 + 2) * 2 + 0] + h3 * Wc[(c0 + 3) * 2 + 0];
            v1 = h0 * Wc[(c0 + 0) * 2 + 1] + h1 * Wc[(c0 + 1) * 2 + 1]
               + h2 * Wc[(c0 + 2) * 2 + 1] + h3 * Wc[(c0 + 3) * 2 + 1];
        }
#pragma unroll
        for (int mask = 1; mask <= 8; mask <<= 1) {
            v0 += __shfl_xor(v0, mask);
            v1 += __shfl_xor(v1, mask);
        }
        if (t == 0) {
            hout[(size_t)node * 2 + 0] = v0 + bc[0];
            hout[(size_t)node * 2 + 1] = v1 + bc[1];
        }
    }
}

extern "C" void kernel_launch(void* const* d_in, const int* in_sizes, int n_in,
                              void* d_out, int out_size, void* d_ws, size_t ws_size,
                              hipStream_t stream) {
    const float* x     = (const float*)d_in[0];
    const int*   ei    = (const int*)d_in[1];
    const float* eattr = (const float*)d_in[2];
    const float* Wl1 = (const float*)d_in[3];
    const float* bl1 = (const float*)d_in[4];
    const float* Wr1 = (const float*)d_in[5];
    const float* br1 = (const float*)d_in[6];
    const float* We1 = (const float*)d_in[7];
    const float* att1 = (const float*)d_in[8];
    const float* bias1 = (const float*)d_in[9];
    const float* Wl2 = (const float*)d_in[10];
    const float* bl2 = (const float*)d_in[11];
    const float* Wr2 = (const float*)d_in[12];
    const float* br2 = (const float*)d_in[13];
    const float* We2 = (const float*)d_in[14];
    const float* att2 = (const float*)d_in[15];
    const float* bias2 = (const float*)d_in[16];
    const float* Wc = (const float*)d_in[17];
    const float* bc = (const float*)d_in[18];

    const int N = in_sizes[0] / 128;
    const int E = in_sizes[1] / 2;
    const int* src = ei;
    const int* dst = ei + E;

    char* w = (char*)d_ws;
    auto alloc = [&](size_t bytes) {
        char* p = w;
        w += (bytes + 255) & ~(size_t)255;
        return p;
    };
    float*          xl         = (float*)alloc((size_t)N * 64 * 4);
    unsigned short* xlb        = (unsigned short*)alloc((size_t)N * 64 * 2);
    unsigned short* xrb        = (unsigned short*)alloc((size_t)N * 64 * 2);
    float*          hbuf       = (float*)alloc((size_t)N * 64 * 4);
    float*          loop_attr  = (float*)alloc((size_t)N * 32 * 4);
    float*          ex_loop    = (float*)alloc((size_t)N * 4);
    int*            deg_i      = (int*)alloc((size_t)N * 4);
    int*            start      = (int*)alloc((size_t)(N + 1) * 4);
    int*            cursor     = (int*)alloc((size_t)N * 4);
    int*            csum       = (int*)alloc(256 * 4);
    int*            perm       = (int*)alloc((size_t)E * 4);
    int*            src_sorted = (int*)alloc((size_t)E * 4);
    int*            sortpos    = (int*)alloc((size_t)E * 4);
    float*          ex_sorted  = (float*)alloc((size_t)E * 4);

    const int THREADS = 256;
    const int score_blocks = (E + 127) / 128;
    const int loop_blocks = (N + 63) / 64;
    const int node4_blocks = (N + 3) / 4;
    const int edge_blocks = (E + THREADS - 1) / THREADS;
    const int nchunks = (N + 1023) / 1024;

    // ---- CSR by dst (shared by both layers) ----
    hipMemsetAsync(deg_i, 0, (size_t)N * 4, stream);
    hipMemsetAsync(cursor, 0, (size_t)N * 4, stream);
    k_hist<<<edge_blocks, THREADS, 0, stream>>>(dst, E, deg_i);
    k_scan_chunk<<<nchunks, 1024, 0, stream>>>(deg_i, start, csum, N);
    k_scan_top<<<1, 64, 0, stream>>>(csum, nchunks, start, N);
    k_scan_apply<<<(N + THREADS - 1) / THREADS, THREADS, 0, stream>>>(start, csum, N);
    k_fill<<<edge_blocks, THREADS, 0, stream>>>(src, dst, E, start, cursor,
                                                perm, src_sorted, sortpos);
    k_loop_csr<<<node4_blocks, THREADS, 0, stream>>>(eattr, perm, start, loop_attr, N);

    // ---- layer 1 ----
    k_node_transform<128><<<node4_blocks, THREADS, 0, stream>>>(x, Wl1, bl1, Wr1, br1,
                                                                xl, xlb, xrb, N);
    k_edge_score<<<score_blocks, THREADS, 0, stream>>>(
        xlb, xrb, eattr, We1, att1, src, dst, sortpos, E, ex_sorted);
    k_loop_score<<<loop_blocks, THREADS, 0, stream>>>(xlb, xrb, loop_attr, We1, att1, N, ex_loop);
    k_node_aggr<false><<<node4_blocks, THREADS, 0, stream>>>(xl, start, src_sorted, ex_sorted,
                                                             ex_loop, bias1, Wc, bc, hbuf, N);

    // ---- layer 2 ----
    k_node_transform<64><<<node4_blocks, THREADS, 0, stream>>>(hbuf, Wl2, bl2, Wr2, br2,
                                                               xl, xlb, xrb, N);
    k_loop_score<<<loop_blocks, THREADS, 0, stream>>>(xlb, xrb, loop_attr, We2, att2, N, ex_loop);
    k_edge_score<<<score_blocks, THREADS, 0, stream>>>(
        xlb, xrb, eattr, We2, att2, src, dst, sortpos, E, ex_sorted);
    k_node_aggr<true><<<node4_blocks, THREADS, 0, stream>>>(xl, start, src_sorted, ex_sorted,
                                                            ex_loop, bias2, Wc, bc, (float*)d_out, N);
}